// Round 8
// baseline (101.946 us; speedup 1.0000x reference)
//
#include <hip/hip_runtime.h>

#define HH 256
#define WW 256
#define NPIX (2 * HH * WW)   // 131072 (B=2)
#define NC 48
#define NB 31
#define TP 192        // table pairs per channel: x in [-1.5,1.5], h=1/64

// ---- main-path geometry: 32x64 output tile, 2x4 px per thread ----
#define OTY 32
#define OTX 64
#define PTY 38        // phi tile rows = OTY+6
#define PTX 70        // phi tile cols = OTX+6
#define PSTR2 76      // phi stride (f32)
#define UTY 44        // u tile rows = OTY+12
#define UTX 76        // u tile cols = OTX+12
#define USTR2 84      // u stride (f32)
#define N1ITEM 684    // conv1 items: 38 rows x 18 col-strips

// ---- legacy (fallback) geometry: 32x32 tile, 1x4 px per thread ----
#define OT 32
#define PT 38
#define PSTR 44
#define UT 44
#define USTR 52

// r22: bank-conflict fix. The 9e6 SQ_LDS_BANK_CONFLICT that survived
// every round was NOT the table gathers (r15 A/B: counter stayed 8.5e6
// with gathers moved to global) -- it is conv1's COLUMN-MAJOR item
// order: consecutive lanes = consecutive rows pr, stride 84 (mod 32 =
// 20, period-8 bank pattern) -> lanes 8 apart hit the same 4-bank group
// at different addresses = ~5-way conflict on every window ds_read_b128
// and phi ds_write_b128 (~35K cy/CU = ~14.6us serialized of a ~39us
// kernel). conv2 (lanes 0..15 = same row, consecutive columns) is
// already minimal -- verified 8 bank-cycles/wave. Fix: conv1 items go
// ROW-MAJOR (pr = gi/18, pc = (gi%18)*4): a wave = ~4 rows x 18
// consecutive strips -> banks tile 4s mod 32, ~9 cy vs 8 min. Pure
// thread->item remap; per-item FMA order untouched -> bit-identical.
// Hard-won constraints (do not violate):
//  - all per-lane accumulators NAMED SCALARS (r3: arrays -> 700 MB spill)
//  - conv1 dy loop unroll-pinned, SW row-pipeline kept (r17/r20/r21)
//  - 4-px-wide items (r6: 8-px -> spill AND worse tail util)
//  - atomic combine is a 34 us loss (r13)
//  - gather pipe speed-invariant LDS vs global (r14/r15): both ~48-61cy
//    serialized per wave-gather on their resp. pipes -- intrinsic
//  - table fusion loses (r16); occupancy saturates ~16 waves/CU (r17/r20)
//  - work-per-thread 2x4 tile recovers r20's per-block-cost loss (r21)

// ---- Build the 48 phi tables once as (value, delta) pairs for 1-read lerp.
__global__ __launch_bounds__(256)
void tnrd_table(const float* __restrict__ wr, float2* __restrict__ tab)
{
    const int ch = blockIdx.x;
    const float* rc = wr + ch * NB;
    for (int j = threadIdx.x; j < TP; j += 256) {
        float v0 = 0.f, v1 = 0.f;
        float x0 = fmaf((float)j, 1.0f / 64.0f, -1.5f);
        float x1 = x0 + 1.0f / 64.0f;
        #pragma unroll
        for (int k = 0; k < NB; ++k) {
            float mu = -1.f + (float)k * (1.f / 15.f);
            float d0 = x0 - mu, d1 = x1 - mu;
            float w = rc[k];
            v0 = fmaf(w, __expf(-50.f * d0 * d0), v0);
            v1 = fmaf(w, __expf(-50.f * d1 * d1), v1);
        }
        tab[ch * TP + j] = make_float2(v0, v1 - v0);
    }
}

// conv1 inner step: window scalars s0..s3, both channels' weights
#define F1STEP(WI, s0, s1, s2, s3)                                      \
    { float fa = wa[WI], fb = wb[WI];                                   \
      a0 = fmaf(s0, fa, a0); a1 = fmaf(s1, fa, a1);                     \
      a2 = fmaf(s2, fa, a2); a3 = fmaf(s3, fa, a3);                     \
      b0 = fmaf(s0, fb, b0); b1 = fmaf(s1, fb, b1);                     \
      b2 = fmaf(s2, fb, b2); b3 = fmaf(s3, fb, b3); }

// 7 taps over the 10-float window (q0.xyzw q1.xyzw q2.xy)
#define F1ROW(WA, WB, q0, q1, q2)                                       \
    { const float* wa = (WA); const float* wb = (WB);                   \
      F1STEP(0, q0.x, q0.y, q0.z, q0.w)                                 \
      F1STEP(1, q0.y, q0.z, q0.w, q1.x)                                 \
      F1STEP(2, q0.z, q0.w, q1.x, q1.y)                                 \
      F1STEP(3, q0.w, q1.x, q1.y, q1.z)                                 \
      F1STEP(4, q1.x, q1.y, q1.z, q1.w)                                 \
      F1STEP(5, q1.y, q1.z, q1.w, q2.x)                                 \
      F1STEP(6, q1.z, q1.w, q2.x, q2.y) }

// table lerp from global (L1-resident 18KB table), named temps only
#define LERP1(res, aval, T)                                             \
    { float t_ = fminf(fmaxf(fmaf(aval, 64.f, 96.f), 0.f), 191.999f);   \
      float fj_ = floorf(t_);                                           \
      float2 e_ = (T)[(int)fj_];            /* global_load_dwordx2 */   \
      res = fmaf(t_ - fj_, e_.y, e_.x); }

// conv2 inner step (flipped weights), both channels, generic accumulators
#define C2STEPG(WI, s0, s1, s2, s3, t0, t1, t2, t3)                     \
    { float fa = wra[WI], fb = wrb[WI];                                 \
      q0 = fmaf(s0, fa, q0); q1 = fmaf(s1, fa, q1);                     \
      q2 = fmaf(s2, fa, q2); q3 = fmaf(s3, fa, q3);                     \
      q0 = fmaf(t0, fb, q0); q1 = fmaf(t1, fb, q1);                     \
      q2 = fmaf(t2, fb, q2); q3 = fmaf(t3, fb, q3); }

// full dx sweep (dx ascending 0..6 <=> WI descending 6..0, both channels)
#define C2SWEEP()                                                       \
    C2STEPG(6, A0.x, A0.y, A0.z, A0.w, B0.x, B0.y, B0.z, B0.w)          \
    C2STEPG(5, A0.y, A0.z, A0.w, A1.x, B0.y, B0.z, B0.w, B1.x)          \
    C2STEPG(4, A0.z, A0.w, A1.x, A1.y, B0.z, B0.w, B1.x, B1.y)          \
    C2STEPG(3, A0.w, A1.x, A1.y, A1.z, B0.w, B1.x, B1.y, B1.z)          \
    C2STEPG(2, A1.x, A1.y, A1.z, A1.w, B1.x, B1.y, B1.z, B1.w)          \
    C2STEPG(1, A1.y, A1.z, A1.w, A2.x, B1.y, B1.z, B1.w, B2.x)          \
    C2STEPG(0, A1.z, A1.w, A2.x, A2.y, B1.z, B1.w, B2.x, B2.y)

// ---- main kernel: 2ch/block, 32x64 tile, 2x4 px/thread ----
__global__ __launch_bounds__(256, 4)
void tnrd_main_2x(const float* __restrict__ u,
                  const float* __restrict__ wf,    // filters [48][49]
                  const float2* __restrict__ tab,  // phi tables [48][TP]
                  float* __restrict__ part)
{
    __shared__ __align__(16) float u_s[UTY * USTR2];        // 14784 B
    __shared__ __align__(16) float phi_s[2][PTY * PSTR2];   // 23104 B

    const int tid = threadIdx.x;
    const int bx = blockIdx.x, by = blockIdx.y;          // 4 x 8 tiles
    const int b = blockIdx.z / 24, g = blockIdx.z % 24;
    const int c0 = g * 2;

    // ---- stage u tile (6-halo, zero-padded incl. stride pad) ----
    const int uy0 = by * OTY - 6, ux0 = bx * OTX - 6;
    const float* ub = u + b * (HH * WW);
    for (int i = tid; i < UTY * USTR2; i += 256) {
        int r = i / USTR2, c = i - r * USTR2;
        int gy = uy0 + r, gx = ux0 + c;
        float v = 0.f;
        if (c < UTX && (unsigned)gy < HH && (unsigned)gx < WW)
            v = ub[gy * WW + gx];
        u_s[i] = v;
    }
    __syncthreads();

    const int py0 = by * OTY - 3, px0 = bx * OTX - 3;

    // ---- conv1 + RBF lerp into planes phi_s[0]/phi_s[1] ----
    {
        const float* wA = wf + c0 * 49;            // block-uniform s_load
        const float* wB = wA + 49;
        const float2* tA = tab + c0 * TP;          // global, L1-hot
        const float2* tB = tA + TP;
        // 684 items = 38 rows x 18 col-strips, ROW-MAJOR (r22: a wave
        // spans ~4 rows x 18 consecutive strips -> conflict-free b128)
        for (int p = 0; p < 3; ++p) {
            const int gi = tid + p * 256;
            if (gi < N1ITEM) {
                const int pr = gi / 18, pc = (gi % 18) * 4;
                float a0 = 0.f, a1 = 0.f, a2 = 0.f, a3 = 0.f;
                float b0 = 0.f, b1 = 0.f, b2 = 0.f, b3 = 0.f;
                const float* bptr = &u_s[pr * USTR2 + pc];

                // software pipeline: load row dy+1 before consuming row dy
                float4 c0v = *(const float4*)(bptr);
                float4 c1v = *(const float4*)(bptr + 4);
                float2 c2v = *(const float2*)(bptr + 8);
                #pragma unroll 1
                for (int dy = 0; dy < 6; ++dy) {
                    const float* nr = bptr + (dy + 1) * USTR2;
                    float4 n0 = *(const float4*)(nr);
                    float4 n1 = *(const float4*)(nr + 4);
                    float2 n2 = *(const float2*)(nr + 8);
                    F1ROW(wA + dy * 7, wB + dy * 7, c0v, c1v, c2v)
                    c0v = n0; c1v = n1; c2v = n2;
                }
                F1ROW(wA + 42, wB + 42, c0v, c1v, c2v)   // epilogue dy=6

                // ---- 1-gather lerp; phi = 0 outside image ----
                const int gy = py0 + pr;
                const bool rowok = (unsigned)gy < HH;
                const bool ok0 = rowok && (unsigned)(px0 + pc + 0) < WW;
                const bool ok1 = rowok && (unsigned)(px0 + pc + 1) < WW;
                const bool ok2 = rowok && (unsigned)(px0 + pc + 2) < WW;
                const bool ok3 = rowok && (unsigned)(px0 + pc + 3) < WW;
                float pA0, pA1, pA2, pA3, pB0, pB1, pB2, pB3;
                LERP1(pA0, a0, tA) LERP1(pB0, b0, tB)
                LERP1(pA1, a1, tA) LERP1(pB1, b1, tB)
                LERP1(pA2, a2, tA) LERP1(pB2, b2, tB)
                LERP1(pA3, a3, tA) LERP1(pB3, b3, tB)
                pA0 = ok0 ? pA0 : 0.f;  pB0 = ok0 ? pB0 : 0.f;
                pA1 = ok1 ? pA1 : 0.f;  pB1 = ok1 ? pB1 : 0.f;
                pA2 = ok2 ? pA2 : 0.f;  pB2 = ok2 ? pB2 : 0.f;
                pA3 = ok3 ? pA3 : 0.f;  pB3 = ok3 ? pB3 : 0.f;
                *(float4*)(&phi_s[0][pr * PSTR2 + pc]) =
                    make_float4(pA0, pA1, pA2, pA3);      // ds_write_b128
                *(float4*)(&phi_s[1][pr * PSTR2 + pc]) =
                    make_float4(pB0, pB1, pB2, pB3);      // ds_write_b128
            }
        }
    }
    __syncthreads();

    // ---- conv2: 2x4 px per thread (rows 2tr, 2tr+1; cols 4tc..4tc+3) ----
    {
        const int tr = tid >> 4;        // 0..15 -> rows 2tr, 2tr+1
        const int ox = (tid & 15) * 4;  // 0..60
        const float* wA = wf + c0 * 49;
        const float* wB = wA + 49;
        float o00 = 0.f, o01 = 0.f, o02 = 0.f, o03 = 0.f;   // row 2tr
        float o10 = 0.f, o11 = 0.f, o12 = 0.f, o13 = 0.f;   // row 2tr+1

        // tile rows 2tr+dyt, dyt=0..7; row0 uses dyt 0..6 (wrow 6-dyt),
        // row1 uses dyt 1..7 (wrow 7-dyt) -> per-acc dy order unchanged
        #pragma unroll
        for (int dyt = 0; dyt < 8; ++dyt) {
            const float* rA = &phi_s[0][(2 * tr + dyt) * PSTR2 + ox];
            const float* rB = &phi_s[1][(2 * tr + dyt) * PSTR2 + ox];
            const float4 A0 = *(const float4*)(rA);
            const float4 A1 = *(const float4*)(rA + 4);
            const float2 A2 = *(const float2*)(rA + 8);
            const float4 B0 = *(const float4*)(rB);
            const float4 B1 = *(const float4*)(rB + 4);
            const float2 B2 = *(const float2*)(rB + 8);
            if (dyt < 7) {   // accumulate output row 2tr
                const float* wra = wA + (6 - dyt) * 7;
                const float* wrb = wB + (6 - dyt) * 7;
                float &q0 = o00, &q1 = o01, &q2 = o02, &q3 = o03;
                C2SWEEP()
            }
            if (dyt > 0) {   // accumulate output row 2tr+1
                const float* wra = wA + (7 - dyt) * 7;
                const float* wrb = wB + (7 - dyt) * 7;
                float &q0 = o10, &q1 = o11, &q2 = o12, &q3 = o13;
                C2SWEEP()
            }
        }

        const int gy0 = by * OTY + 2 * tr, gx = bx * OTX + ox;
        float* dst = part + (size_t)g * NPIX + b * (HH * WW) + gy0 * WW + gx;
        *reinterpret_cast<float4*>(dst)      = make_float4(o00, o01, o02, o03);
        *reinterpret_cast<float4*>(dst + WW) = make_float4(o10, o11, o12, o13);
    }
}

// conv2 inner step for legacy kernel (fixed names o0..o3)
#define C2STEP(WI, s0, s1, s2, s3, t0, t1, t2, t3)                      \
    { float fa = wra[WI], fb = wrb[WI];                                 \
      o0 = fmaf(s0, fa, o0); o1 = fmaf(s1, fa, o1);                     \
      o2 = fmaf(s2, fa, o2); o3 = fmaf(s3, fa, o3);                     \
      o0 = fmaf(t0, fb, o0); o1 = fmaf(t1, fb, o1);                     \
      o2 = fmaf(t2, fb, o2); o3 = fmaf(t3, fb, o3); }

// ---- legacy fallback (proven r17/r20 device code), CPG=4/8 ----
template<int CPG>
__global__ __launch_bounds__(256, 6)
void tnrd_main(const float* __restrict__ u,
               const float* __restrict__ wf,
               const float2* __restrict__ tab,
               float* __restrict__ part)
{
    constexpr int NGRP = NC / CPG;
    constexpr int NPASS = CPG / 2;
    __shared__ __align__(16) float u_s[UT * USTR];
    __shared__ __align__(16) float phi_s[2][PT * PSTR];

    const int tid = threadIdx.x;
    const int bx = blockIdx.x, by = blockIdx.y;
    const int b = blockIdx.z / NGRP, g = blockIdx.z % NGRP;
    const int c0g = g * CPG;

    const int uy0 = by * OT - 6, ux0 = bx * OT - 6;
    const float* ub = u + b * (HH * WW);
    for (int i = tid; i < UT * USTR; i += 256) {
        int r = i / USTR, c = i - r * USTR;
        int gy = uy0 + r, gx = ux0 + c;
        float v = 0.f;
        if (c < UT && (unsigned)gy < HH && (unsigned)gx < WW)
            v = ub[gy * WW + gx];
        u_s[i] = v;
    }
    __syncthreads();

    const int oy = tid >> 3;
    const int ox0 = (tid & 7) * 4;
    float o0 = 0.f, o1 = 0.f, o2 = 0.f, o3 = 0.f;
    const int py0 = by * OT - 3, px0 = bx * OT - 3;

    auto conv1_pass = [&](int cp, float* __restrict__ bufA,
                          float* __restrict__ bufB) {
        const float* wA = wf + (c0g + 2 * cp) * 49;
        const float* wB = wA + 49;
        const float2* tA = tab + (c0g + 2 * cp) * TP;
        const float2* tB = tA + TP;
        for (int p = 0; p < 2; ++p) {
            const int gi = tid + p * 256;
            if (gi < PT * 10) {
                const int pr = gi % PT, pc = (gi / PT) * 4;
                float a0 = 0.f, a1 = 0.f, a2 = 0.f, a3 = 0.f;
                float b0 = 0.f, b1 = 0.f, b2 = 0.f, b3 = 0.f;
                const float* bptr = &u_s[pr * USTR + pc];
                float4 c0 = *(const float4*)(bptr);
                float4 c1 = *(const float4*)(bptr + 4);
                float2 c2 = *(const float2*)(bptr + 8);
                #pragma unroll 1
                for (int dy = 0; dy < 6; ++dy) {
                    const float* nr = bptr + (dy + 1) * USTR;
                    float4 n0 = *(const float4*)(nr);
                    float4 n1 = *(const float4*)(nr + 4);
                    float2 n2 = *(const float2*)(nr + 8);
                    F1ROW(wA + dy * 7, wB + dy * 7, c0, c1, c2)
                    c0 = n0; c1 = n1; c2 = n2;
                }
                F1ROW(wA + 42, wB + 42, c0, c1, c2)
                const int gy = py0 + pr;
                const bool rowok = (unsigned)gy < HH;
                const bool ok0 = rowok && (unsigned)(px0 + pc + 0) < WW;
                const bool ok1 = rowok && (unsigned)(px0 + pc + 1) < WW;
                const bool ok2 = rowok && (unsigned)(px0 + pc + 2) < WW;
                const bool ok3 = rowok && (unsigned)(px0 + pc + 3) < WW;
                float pA0, pA1, pA2, pA3, pB0, pB1, pB2, pB3;
                LERP1(pA0, a0, tA) LERP1(pB0, b0, tB)
                LERP1(pA1, a1, tA) LERP1(pB1, b1, tB)
                LERP1(pA2, a2, tA) LERP1(pB2, b2, tB)
                LERP1(pA3, a3, tA) LERP1(pB3, b3, tB)
                pA0 = ok0 ? pA0 : 0.f;  pB0 = ok0 ? pB0 : 0.f;
                pA1 = ok1 ? pA1 : 0.f;  pB1 = ok1 ? pB1 : 0.f;
                pA2 = ok2 ? pA2 : 0.f;  pB2 = ok2 ? pB2 : 0.f;
                pA3 = ok3 ? pA3 : 0.f;  pB3 = ok3 ? pB3 : 0.f;
                *(float4*)(bufA + pr * PSTR + pc) =
                    make_float4(pA0, pA1, pA2, pA3);
                *(float4*)(bufB + pr * PSTR + pc) =
                    make_float4(pB0, pB1, pB2, pB3);
            }
        }
    };

    #pragma unroll 1
    for (int pass = 0; pass < NPASS; ++pass) {
        conv1_pass(pass, phi_s[0], phi_s[1]);
        __syncthreads();
        const float* wA = wf + (c0g + 2 * pass) * 49;
        const float* wB = wA + 49;
        const float* pA = phi_s[0];
        const float* pB = phi_s[1];
        for (int dy = 0; dy < 7; ++dy) {
            const float* rA = pA + (oy + dy) * PSTR + ox0;
            const float* rB = pB + (oy + dy) * PSTR + ox0;
            const float4 A0 = *(const float4*)(rA);
            const float4 A1 = *(const float4*)(rA + 4);
            const float2 A2 = *(const float2*)(rA + 8);
            const float4 B0 = *(const float4*)(rB);
            const float4 B1 = *(const float4*)(rB + 4);
            const float2 B2 = *(const float2*)(rB + 8);
            const float* wra = wA + (6 - dy) * 7;
            const float* wrb = wB + (6 - dy) * 7;
            C2STEP(6, A0.x, A0.y, A0.z, A0.w, B0.x, B0.y, B0.z, B0.w)
            C2STEP(5, A0.y, A0.z, A0.w, A1.x, B0.y, B0.z, B0.w, B1.x)
            C2STEP(4, A0.z, A0.w, A1.x, A1.y, B0.z, B0.w, B1.x, B1.y)
            C2STEP(3, A0.w, A1.x, A1.y, A1.z, B0.w, B1.x, B1.y, B1.z)
            C2STEP(2, A1.x, A1.y, A1.z, A1.w, B1.x, B1.y, B1.z, B1.w)
            C2STEP(1, A1.y, A1.z, A1.w, A2.x, B1.y, B1.z, B1.w, B2.x)
            C2STEP(0, A1.z, A1.w, A2.x, A2.y, B1.z, B1.w, B2.x, B2.y)
        }
        if (pass < NPASS - 1) __syncthreads();
    }

    const int gy = by * OT + oy, gx = bx * OT + ox0;
    float4 v4 = make_float4(o0, o1, o2, o3);
    *reinterpret_cast<float4*>(part + (size_t)g * NPIX + b * (HH * WW)
                               + gy * WW + gx) = v4;
}

template<int NGRP>
__global__ __launch_bounds__(256)
void combine_kernel(const float* __restrict__ u,
                    const float* __restrict__ f,
                    const float* __restrict__ lam,
                    const float* __restrict__ part,
                    float* __restrict__ out)
{
    int i = blockIdx.x * 256 + threadIdx.x;  // 512 blocks -> NPIX
    float d = 0.f;
    #pragma unroll
    for (int g = 0; g < NGRP; ++g) d += part[g * NPIX + i];
    float lv = lam[0];
    float uv = u[i];
    float fv = f[i];
    out[i] = uv - d - lv * (uv - fv);
}

extern "C" void kernel_launch(void* const* d_in, const int* in_sizes, int n_in,
                              void* d_out, int out_size, void* d_ws, size_t ws_size,
                              hipStream_t stream) {
    const float* u    = (const float*)d_in[0];
    const float* f    = (const float*)d_in[1];
    const float* filt = (const float*)d_in[2];
    const float* rbfw = (const float*)d_in[3];
    const float* lam  = (const float*)d_in[4];
    float* out = (float*)d_out;
    float* part = (float*)d_ws;
    // phi tables overlaid on d_out scratch (48*192 float2 = 18432 floats
    // <= 131072); combine_kernel fully overwrites d_out afterwards.
    float2* tabg = (float2*)d_out;

    tnrd_table<<<NC, 256, 0, stream>>>(rbfw, tabg);
    if (ws_size >= (size_t)24 * NPIX * sizeof(float)) {
        // 24 groups x 2ch, 32x64 tiles, 2x4 px/thread: 1536 blocks
        tnrd_main_2x<<<dim3(WW / OTX, HH / OTY, 48), 256, 0, stream>>>(
            u, filt, tabg, part);
        combine_kernel<24><<<512, 256, 0, stream>>>(u, f, lam, part, out);
    } else if (ws_size >= (size_t)12 * NPIX * sizeof(float)) {
        // r17 structure: 12 groups x 4ch, 6 blocks/CU
        tnrd_main<4><<<dim3(8, 8, 24), 256, 0, stream>>>(u, filt, tabg, part);
        combine_kernel<12><<<512, 256, 0, stream>>>(u, f, lam, part, out);
    } else {
        // smallest-ws fallback: 6 groups x 8ch (r15 structure)
        tnrd_main<8><<<dim3(8, 8, 12), 256, 0, stream>>>(u, filt, tabg, part);
        combine_kernel<6><<<512, 256, 0, stream>>>(u, f, lam, part, out);
    }
}

// Round 9
// 97.833 us; speedup vs baseline: 1.0420x; 1.0420x over previous
//
#include <hip/hip_runtime.h>

#define HH 256
#define WW 256
#define NPIX (2 * HH * WW)   // 131072 (B=2)
#define NC 48
#define NB 31
#define TP 192        // table pairs per channel: x in [-1.5,1.5], h=1/64

// ---- main-path geometry: 32x64 output tile, 2x4 px per thread ----
#define OTY 32
#define OTX 64
#define PTY 38        // phi tile rows = OTY+6
#define PSTR2 76      // phi stride (f32)
#define N1ITEM 684    // conv1 items: 38 rows x 18 col-strips

// ---- padded-u buffer: pad=6 on all sides -> conv1 needs NO bounds and
// every window row base (bx*64+pc) is 16B-aligned ----
#define PADW 272
#define PADN (2 * PADW * PADW)   // 147968 floats

// ---- legacy (fallback) geometry: 32x32 tile, 1x4 px per thread ----
#define OT 32
#define PT 38
#define PSTR 44
#define UT 44
#define USTR 52

// r23: direct-global conv1. r22 (bank-conflict remap) was NEUTRAL ->
// conflicts were never on the critical path (counter = bank-cycles
// absorbed by TLP, not stalls). Remaining per-block costs: u_s staging
// (~60 instr/thread), 2 barriers, LDS 37.9KB capping residency at 4
// blocks/CU (sweet spot is >=6, r17/r20). Fix: zero-padded u copy
// (2x272x272, 592KB, L1/L2-hot; built inside the table kernel, same
// launch count) lets conv1 read global directly, 16B-aligned, no
// bounds: staging + u_s + 1 barrier deleted, LDS -> 23.1KB -> 6
// resident blocks = 24 waves/CU. Window values identical to staged
// zeros; FMA order untouched -> bit-identical (absmax 0.015625).
// Hard-won constraints (do not violate):
//  - all per-lane accumulators NAMED SCALARS (r3: arrays -> 700 MB spill)
//  - conv1 dy loop unroll-pinned, SW row-pipeline kept (r17/r20/r21)
//  - 4-px-wide items (r6); atomic combine loses 34us (r13)
//  - gather pipe speed-invariant (r14/r15); table fusion into main
//    loses (r16); occupancy saturates ~16-24 waves/CU (r17/r20)
//  - work-per-thread 2x4 tile is a win (r21); LDS bank conflicts are
//    NOT on the critical path (r22 A/B neutral)

// ---- table build (48 low blocks) + u zero-padding (all 578 blocks) ----
__global__ __launch_bounds__(256)
void tnrd_table_pad(const float* __restrict__ wr,
                    const float* __restrict__ u,
                    float2* __restrict__ tab,
                    float* __restrict__ upad)
{
    const int bid = blockIdx.x;
    // pad work: 578*256 = 147968 = 2*272*272 exactly
    {
        const int i = bid * 256 + threadIdx.x;
        const int img = i / (PADW * PADW);
        const int rem = i - img * (PADW * PADW);
        const int py = rem / PADW, px = rem - py * PADW;
        const int gy = py - 6, gx = px - 6;
        float v = 0.f;
        if ((unsigned)gy < HH && (unsigned)gx < WW)
            v = u[img * (HH * WW) + gy * WW + gx];
        upad[i] = v;
    }
    // table work: first 48 blocks, one channel each
    if (bid < NC && threadIdx.x < TP) {
        const int j = threadIdx.x;
        const float* rc = wr + bid * NB;
        float v0 = 0.f, v1 = 0.f;
        float x0 = fmaf((float)j, 1.0f / 64.0f, -1.5f);
        float x1 = x0 + 1.0f / 64.0f;
        #pragma unroll
        for (int k = 0; k < NB; ++k) {
            float mu = -1.f + (float)k * (1.f / 15.f);
            float d0 = x0 - mu, d1 = x1 - mu;
            float w = rc[k];
            v0 = fmaf(w, __expf(-50.f * d0 * d0), v0);
            v1 = fmaf(w, __expf(-50.f * d1 * d1), v1);
        }
        tab[bid * TP + j] = make_float2(v0, v1 - v0);
    }
}

// standalone table kernel for the legacy fallback path
__global__ __launch_bounds__(256)
void tnrd_table(const float* __restrict__ wr, float2* __restrict__ tab)
{
    const int ch = blockIdx.x;
    const float* rc = wr + ch * NB;
    for (int j = threadIdx.x; j < TP; j += 256) {
        float v0 = 0.f, v1 = 0.f;
        float x0 = fmaf((float)j, 1.0f / 64.0f, -1.5f);
        float x1 = x0 + 1.0f / 64.0f;
        #pragma unroll
        for (int k = 0; k < NB; ++k) {
            float mu = -1.f + (float)k * (1.f / 15.f);
            float d0 = x0 - mu, d1 = x1 - mu;
            float w = rc[k];
            v0 = fmaf(w, __expf(-50.f * d0 * d0), v0);
            v1 = fmaf(w, __expf(-50.f * d1 * d1), v1);
        }
        tab[ch * TP + j] = make_float2(v0, v1 - v0);
    }
}

// conv1 inner step: window scalars s0..s3, both channels' weights
#define F1STEP(WI, s0, s1, s2, s3)                                      \
    { float fa = wa[WI], fb = wb[WI];                                   \
      a0 = fmaf(s0, fa, a0); a1 = fmaf(s1, fa, a1);                     \
      a2 = fmaf(s2, fa, a2); a3 = fmaf(s3, fa, a3);                     \
      b0 = fmaf(s0, fb, b0); b1 = fmaf(s1, fb, b1);                     \
      b2 = fmaf(s2, fb, b2); b3 = fmaf(s3, fb, b3); }

// 7 taps over the 10-float window (q0.xyzw q1.xyzw q2.xy)
#define F1ROW(WA, WB, q0, q1, q2)                                      \
    { const float* wa = (WA); const float* wb = (WB);                   \
      F1STEP(0, q0.x, q0.y, q0.z, q0.w)                                 \
      F1STEP(1, q0.y, q0.z, q0.w, q1.x)                                 \
      F1STEP(2, q0.z, q0.w, q1.x, q1.y)                                 \
      F1STEP(3, q0.w, q1.x, q1.y, q1.z)                                 \
      F1STEP(4, q1.x, q1.y, q1.z, q1.w)                                 \
      F1STEP(5, q1.y, q1.z, q1.w, q2.x)                                 \
      F1STEP(6, q1.z, q1.w, q2.x, q2.y) }

// table lerp from global (L1-resident 18KB table), named temps only
#define LERP1(res, aval, T)                                             \
    { float t_ = fminf(fmaxf(fmaf(aval, 64.f, 96.f), 0.f), 191.999f);   \
      float fj_ = floorf(t_);                                           \
      float2 e_ = (T)[(int)fj_];            /* global_load_dwordx2 */   \
      res = fmaf(t_ - fj_, e_.y, e_.x); }

// conv2 inner step (flipped weights), both channels, generic accumulators
#define C2STEPG(WI, s0, s1, s2, s3, t0, t1, t2, t3)                     \
    { float fa = wra[WI], fb = wrb[WI];                                 \
      q0 = fmaf(s0, fa, q0); q1 = fmaf(s1, fa, q1);                     \
      q2 = fmaf(s2, fa, q2); q3 = fmaf(s3, fa, q3);                     \
      q0 = fmaf(t0, fb, q0); q1 = fmaf(t1, fb, q1);                     \
      q2 = fmaf(t2, fb, q2); q3 = fmaf(t3, fb, q3); }

// full dx sweep (dx ascending 0..6 <=> WI descending 6..0, both channels)
#define C2SWEEP()                                                       \
    C2STEPG(6, A0.x, A0.y, A0.z, A0.w, B0.x, B0.y, B0.z, B0.w)          \
    C2STEPG(5, A0.y, A0.z, A0.w, A1.x, B0.y, B0.z, B0.w, B1.x)          \
    C2STEPG(4, A0.z, A0.w, A1.x, A1.y, B0.z, B0.w, B1.x, B1.y)          \
    C2STEPG(3, A0.w, A1.x, A1.y, A1.z, B0.w, B1.x, B1.y, B1.z)          \
    C2STEPG(2, A1.x, A1.y, A1.z, A1.w, B1.x, B1.y, B1.z, B1.w)          \
    C2STEPG(1, A1.y, A1.z, A1.w, A2.x, B1.y, B1.z, B1.w, B2.x)          \
    C2STEPG(0, A1.z, A1.w, A2.x, A2.y, B1.z, B1.w, B2.x, B2.y)

// ---- main kernel: 2ch/block, 32x64 tile, 2x4 px/thread, no u staging ----
__global__ __launch_bounds__(256, 6)
void tnrd_main_2xg(const float* __restrict__ upad,  // padded u [2][272][272]
                   const float* __restrict__ wf,    // filters [48][49]
                   const float2* __restrict__ tab,  // phi tables [48][TP]
                   float* __restrict__ part)
{
    __shared__ __align__(16) float phi_s[2][PTY * PSTR2];   // 23104 B

    const int tid = threadIdx.x;
    const int bx = blockIdx.x, by = blockIdx.y;          // 4 x 8 tiles
    const int b = blockIdx.z / 24, g = blockIdx.z % 24;
    const int c0 = g * 2;

    const int py0 = by * OTY - 3, px0 = bx * OTX - 3;

    // ---- conv1 + RBF lerp into planes phi_s[0]/phi_s[1] ----
    {
        const float* wA = wf + c0 * 49;            // block-uniform s_load
        const float* wB = wA + 49;
        const float2* tA = tab + c0 * TP;          // global, L1-hot
        const float2* tB = tA + TP;
        const float* ubase = upad + b * (PADW * PADW);
        // 684 items = 38 rows x 18 col-strips, row-major
        for (int p = 0; p < 3; ++p) {
            const int gi = tid + p * 256;
            if (gi < N1ITEM) {
                const int pr = gi / 18, pc = (gi % 18) * 4;
                float a0 = 0.f, a1 = 0.f, a2 = 0.f, a3 = 0.f;
                float b0 = 0.f, b1 = 0.f, b2 = 0.f, b3 = 0.f;
                // window row dy at padded row (py0+pr+3+dy), col bx*64+pc
                // (pad=6 makes this 16B-aligned; all indices in-bounds)
                const float* bptr = ubase + (py0 + pr + 3) * PADW
                                          + (bx * OTX + pc);

                // software pipeline: load row dy+1 before consuming row dy
                float4 c0v = *(const float4*)(bptr);
                float4 c1v = *(const float4*)(bptr + 4);
                float2 c2v = *(const float2*)(bptr + 8);
                #pragma unroll 1
                for (int dy = 0; dy < 6; ++dy) {
                    const float* nr = bptr + (dy + 1) * PADW;
                    float4 n0 = *(const float4*)(nr);
                    float4 n1 = *(const float4*)(nr + 4);
                    float2 n2 = *(const float2*)(nr + 8);
                    F1ROW(wA + dy * 7, wB + dy * 7, c0v, c1v, c2v)
                    c0v = n0; c1v = n1; c2v = n2;
                }
                F1ROW(wA + 42, wB + 42, c0v, c1v, c2v)   // epilogue dy=6

                // ---- 1-gather lerp; phi = 0 outside image ----
                const int gy = py0 + pr;
                const bool rowok = (unsigned)gy < HH;
                const bool ok0 = rowok && (unsigned)(px0 + pc + 0) < WW;
                const bool ok1 = rowok && (unsigned)(px0 + pc + 1) < WW;
                const bool ok2 = rowok && (unsigned)(px0 + pc + 2) < WW;
                const bool ok3 = rowok && (unsigned)(px0 + pc + 3) < WW;
                float pA0, pA1, pA2, pA3, pB0, pB1, pB2, pB3;
                LERP1(pA0, a0, tA) LERP1(pB0, b0, tB)
                LERP1(pA1, a1, tA) LERP1(pB1, b1, tB)
                LERP1(pA2, a2, tA) LERP1(pB2, b2, tB)
                LERP1(pA3, a3, tA) LERP1(pB3, b3, tB)
                pA0 = ok0 ? pA0 : 0.f;  pB0 = ok0 ? pB0 : 0.f;
                pA1 = ok1 ? pA1 : 0.f;  pB1 = ok1 ? pB1 : 0.f;
                pA2 = ok2 ? pA2 : 0.f;  pB2 = ok2 ? pB2 : 0.f;
                pA3 = ok3 ? pA3 : 0.f;  pB3 = ok3 ? pB3 : 0.f;
                *(float4*)(&phi_s[0][pr * PSTR2 + pc]) =
                    make_float4(pA0, pA1, pA2, pA3);      // ds_write_b128
                *(float4*)(&phi_s[1][pr * PSTR2 + pc]) =
                    make_float4(pB0, pB1, pB2, pB3);      // ds_write_b128
            }
        }
    }
    __syncthreads();

    // ---- conv2: 2x4 px per thread (rows 2tr, 2tr+1; cols 4tc..4tc+3) ----
    {
        const int tr = tid >> 4;        // 0..15 -> rows 2tr, 2tr+1
        const int ox = (tid & 15) * 4;  // 0..60
        const float* wA = wf + c0 * 49;
        const float* wB = wA + 49;
        float o00 = 0.f, o01 = 0.f, o02 = 0.f, o03 = 0.f;   // row 2tr
        float o10 = 0.f, o11 = 0.f, o12 = 0.f, o13 = 0.f;   // row 2tr+1

        // tile rows 2tr+dyt, dyt=0..7; row0 uses dyt 0..6 (wrow 6-dyt),
        // row1 uses dyt 1..7 (wrow 7-dyt) -> per-acc dy order unchanged
        #pragma unroll
        for (int dyt = 0; dyt < 8; ++dyt) {
            const float* rA = &phi_s[0][(2 * tr + dyt) * PSTR2 + ox];
            const float* rB = &phi_s[1][(2 * tr + dyt) * PSTR2 + ox];
            const float4 A0 = *(const float4*)(rA);
            const float4 A1 = *(const float4*)(rA + 4);
            const float2 A2 = *(const float2*)(rA + 8);
            const float4 B0 = *(const float4*)(rB);
            const float4 B1 = *(const float4*)(rB + 4);
            const float2 B2 = *(const float2*)(rB + 8);
            if (dyt < 7) {   // accumulate output row 2tr
                const float* wra = wA + (6 - dyt) * 7;
                const float* wrb = wB + (6 - dyt) * 7;
                float &q0 = o00, &q1 = o01, &q2 = o02, &q3 = o03;
                C2SWEEP()
            }
            if (dyt > 0) {   // accumulate output row 2tr+1
                const float* wra = wA + (7 - dyt) * 7;
                const float* wrb = wB + (7 - dyt) * 7;
                float &q0 = o10, &q1 = o11, &q2 = o12, &q3 = o13;
                C2SWEEP()
            }
        }

        const int gy0 = by * OTY + 2 * tr, gx = bx * OTX + ox;
        float* dst = part + (size_t)g * NPIX + b * (HH * WW) + gy0 * WW + gx;
        *reinterpret_cast<float4*>(dst)      = make_float4(o00, o01, o02, o03);
        *reinterpret_cast<float4*>(dst + WW) = make_float4(o10, o11, o12, o13);
    }
}

// conv2 inner step for legacy kernel (fixed names o0..o3)
#define C2STEP(WI, s0, s1, s2, s3, t0, t1, t2, t3)                      \
    { float fa = wra[WI], fb = wrb[WI];                                 \
      o0 = fmaf(s0, fa, o0); o1 = fmaf(s1, fa, o1);                     \
      o2 = fmaf(s2, fa, o2); o3 = fmaf(s3, fa, o3);                     \
      o0 = fmaf(t0, fb, o0); o1 = fmaf(t1, fb, o1);                     \
      o2 = fmaf(t2, fb, o2); o3 = fmaf(t3, fb, o3); }

// ---- legacy fallback (proven r17/r20 device code), CPG=4/8 ----
template<int CPG>
__global__ __launch_bounds__(256, 6)
void tnrd_main(const float* __restrict__ u,
               const float* __restrict__ wf,
               const float2* __restrict__ tab,
               float* __restrict__ part)
{
    constexpr int NGRP = NC / CPG;
    constexpr int NPASS = CPG / 2;
    __shared__ __align__(16) float u_s[UT * USTR];
    __shared__ __align__(16) float phi_s[2][PT * PSTR];

    const int tid = threadIdx.x;
    const int bx = blockIdx.x, by = blockIdx.y;
    const int b = blockIdx.z / NGRP, g = blockIdx.z % NGRP;
    const int c0g = g * CPG;

    const int uy0 = by * OT - 6, ux0 = bx * OT - 6;
    const float* ub = u + b * (HH * WW);
    for (int i = tid; i < UT * USTR; i += 256) {
        int r = i / USTR, c = i - r * USTR;
        int gy = uy0 + r, gx = ux0 + c;
        float v = 0.f;
        if (c < UT && (unsigned)gy < HH && (unsigned)gx < WW)
            v = ub[gy * WW + gx];
        u_s[i] = v;
    }
    __syncthreads();

    const int oy = tid >> 3;
    const int ox0 = (tid & 7) * 4;
    float o0 = 0.f, o1 = 0.f, o2 = 0.f, o3 = 0.f;
    const int py0 = by * OT - 3, px0 = bx * OT - 3;

    auto conv1_pass = [&](int cp, float* __restrict__ bufA,
                          float* __restrict__ bufB) {
        const float* wA = wf + (c0g + 2 * cp) * 49;
        const float* wB = wA + 49;
        const float2* tA = tab + (c0g + 2 * cp) * TP;
        const float2* tB = tA + TP;
        for (int p = 0; p < 2; ++p) {
            const int gi = tid + p * 256;
            if (gi < PT * 10) {
                const int pr = gi % PT, pc = (gi / PT) * 4;
                float a0 = 0.f, a1 = 0.f, a2 = 0.f, a3 = 0.f;
                float b0 = 0.f, b1 = 0.f, b2 = 0.f, b3 = 0.f;
                const float* bptr = &u_s[pr * USTR + pc];
                float4 c0 = *(const float4*)(bptr);
                float4 c1 = *(const float4*)(bptr + 4);
                float2 c2 = *(const float2*)(bptr + 8);
                #pragma unroll 1
                for (int dy = 0; dy < 6; ++dy) {
                    const float* nr = bptr + (dy + 1) * USTR;
                    float4 n0 = *(const float4*)(nr);
                    float4 n1 = *(const float4*)(nr + 4);
                    float2 n2 = *(const float2*)(nr + 8);
                    F1ROW(wA + dy * 7, wB + dy * 7, c0, c1, c2)
                    c0 = n0; c1 = n1; c2 = n2;
                }
                F1ROW(wA + 42, wB + 42, c0, c1, c2)
                const int gy = py0 + pr;
                const bool rowok = (unsigned)gy < HH;
                const bool ok0 = rowok && (unsigned)(px0 + pc + 0) < WW;
                const bool ok1 = rowok && (unsigned)(px0 + pc + 1) < WW;
                const bool ok2 = rowok && (unsigned)(px0 + pc + 2) < WW;
                const bool ok3 = rowok && (unsigned)(px0 + pc + 3) < WW;
                float pA0, pA1, pA2, pA3, pB0, pB1, pB2, pB3;
                LERP1(pA0, a0, tA) LERP1(pB0, b0, tB)
                LERP1(pA1, a1, tA) LERP1(pB1, b1, tB)
                LERP1(pA2, a2, tA) LERP1(pB2, b2, tB)
                LERP1(pA3, a3, tA) LERP1(pB3, b3, tB)
                pA0 = ok0 ? pA0 : 0.f;  pB0 = ok0 ? pB0 : 0.f;
                pA1 = ok1 ? pA1 : 0.f;  pB1 = ok1 ? pB1 : 0.f;
                pA2 = ok2 ? pA2 : 0.f;  pB2 = ok2 ? pB2 : 0.f;
                pA3 = ok3 ? pA3 : 0.f;  pB3 = ok3 ? pB3 : 0.f;
                *(float4*)(bufA + pr * PSTR + pc) =
                    make_float4(pA0, pA1, pA2, pA3);
                *(float4*)(bufB + pr * PSTR + pc) =
                    make_float4(pB0, pB1, pB2, pB3);
            }
        }
    };

    #pragma unroll 1
    for (int pass = 0; pass < NPASS; ++pass) {
        conv1_pass(pass, phi_s[0], phi_s[1]);
        __syncthreads();
        const float* wA = wf + (c0g + 2 * pass) * 49;
        const float* wB = wA + 49;
        const float* pA = phi_s[0];
        const float* pB = phi_s[1];
        for (int dy = 0; dy < 7; ++dy) {
            const float* rA = pA + (oy + dy) * PSTR + ox0;
            const float* rB = pB + (oy + dy) * PSTR + ox0;
            const float4 A0 = *(const float4*)(rA);
            const float4 A1 = *(const float4*)(rA + 4);
            const float2 A2 = *(const float2*)(rA + 8);
            const float4 B0 = *(const float4*)(rB);
            const float4 B1 = *(const float4*)(rB + 4);
            const float2 B2 = *(const float2*)(rB + 8);
            const float* wra = wA + (6 - dy) * 7;
            const float* wrb = wB + (6 - dy) * 7;
            C2STEP(6, A0.x, A0.y, A0.z, A0.w, B0.x, B0.y, B0.z, B0.w)
            C2STEP(5, A0.y, A0.z, A0.w, A1.x, B0.y, B0.z, B0.w, B1.x)
            C2STEP(4, A0.z, A0.w, A1.x, A1.y, B0.z, B0.w, B1.x, B1.y)
            C2STEP(3, A0.w, A1.x, A1.y, A1.z, B0.w, B1.x, B1.y, B1.z)
            C2STEP(2, A1.x, A1.y, A1.z, A1.w, B1.x, B1.y, B1.z, B1.w)
            C2STEP(1, A1.y, A1.z, A1.w, A2.x, B1.y, B1.z, B1.w, B2.x)
            C2STEP(0, A1.z, A1.w, A2.x, A2.y, B1.z, B1.w, B2.x, B2.y)
        }
        if (pass < NPASS - 1) __syncthreads();
    }

    const int gy = by * OT + oy, gx = bx * OT + ox0;
    float4 v4 = make_float4(o0, o1, o2, o3);
    *reinterpret_cast<float4*>(part + (size_t)g * NPIX + b * (HH * WW)
                               + gy * WW + gx) = v4;
}

template<int NGRP>
__global__ __launch_bounds__(256)
void combine_kernel(const float* __restrict__ u,
                    const float* __restrict__ f,
                    const float* __restrict__ lam,
                    const float* __restrict__ part,
                    float* __restrict__ out)
{
    int i = blockIdx.x * 256 + threadIdx.x;  // 512 blocks -> NPIX
    float d = 0.f;
    #pragma unroll
    for (int g = 0; g < NGRP; ++g) d += part[g * NPIX + i];
    float lv = lam[0];
    float uv = u[i];
    float fv = f[i];
    out[i] = uv - d - lv * (uv - fv);
}

extern "C" void kernel_launch(void* const* d_in, const int* in_sizes, int n_in,
                              void* d_out, int out_size, void* d_ws, size_t ws_size,
                              hipStream_t stream) {
    const float* u    = (const float*)d_in[0];
    const float* f    = (const float*)d_in[1];
    const float* filt = (const float*)d_in[2];
    const float* rbfw = (const float*)d_in[3];
    const float* lam  = (const float*)d_in[4];
    float* out = (float*)d_out;
    float* part = (float*)d_ws;
    // phi tables overlaid on d_out scratch (48*192 float2 = 18432 floats
    // <= 131072); combine_kernel fully overwrites d_out afterwards.
    float2* tabg = (float2*)d_out;

    const size_t need = ((size_t)24 * NPIX + PADN) * sizeof(float);
    if (ws_size >= need) {
        // padded u lives after the 24 part planes
        float* upad = part + (size_t)24 * NPIX;
        // 578 blocks: all pad u (578*256 == 2*272*272); first 48 build tables
        tnrd_table_pad<<<PADN / 256, 256, 0, stream>>>(rbfw, u, tabg, upad);
        // 24 groups x 2ch, 32x64 tiles, 2x4 px/thread, direct-global conv1
        tnrd_main_2xg<<<dim3(WW / OTX, HH / OTY, 48), 256, 0, stream>>>(
            upad, filt, tabg, part);
        combine_kernel<24><<<512, 256, 0, stream>>>(u, f, lam, part, out);
    } else if (ws_size >= (size_t)12 * NPIX * sizeof(float)) {
        // r17 structure: 12 groups x 4ch, 6 blocks/CU
        tnrd_table<<<NC, 256, 0, stream>>>(rbfw, tabg);
        tnrd_main<4><<<dim3(8, 8, 24), 256, 0, stream>>>(u, filt, tabg, part);
        combine_kernel<12><<<512, 256, 0, stream>>>(u, f, lam, part, out);
    } else {
        // smallest-ws fallback: 6 groups x 8ch (r15 structure)
        tnrd_table<<<NC, 256, 0, stream>>>(rbfw, tabg);
        tnrd_main<8><<<dim3(8, 8, 12), 256, 0, stream>>>(u, filt, tabg, part);
        combine_kernel<6><<<512, 256, 0, stream>>>(u, f, lam, part, out);
    }
}

// Round 10
// 95.833 us; speedup vs baseline: 1.0638x; 1.0209x over previous
//
#include <hip/hip_runtime.h>

#define HH 256
#define WW 256
#define NPIX (2 * HH * WW)   // 131072 (B=2)
#define NC 48
#define NB 31
#define TP 192        // table pairs per channel: x in [-1.5,1.5], h=1/64

// ---- main-path geometry: 32x64 output tile, 2x4 px per thread ----
#define OTY 32
#define OTX 64
#define PTY 38        // phi tile rows = OTY+6
#define PSTR2 76      // phi stride (f32)
#define N1ITEM 684    // conv1 items: 38 rows x 18 col-strips

// ---- padded-u buffer: pad=6 on all sides ----
#define PADW 272
#define PADN (2 * PADW * PADW)   // 147968 floats

// packed weight tables (built in prep kernel)
#define PW1N (24 * 49)       // conv1: (wA[k], wB[k]) per channel-pair
#define PW2N (48 * 8 * 7)    // conv2: (w_row0, w_row1) per ch, dyt, wi

// ---- legacy (fallback) geometry ----
#define OT 32
#define PT 38
#define PSTR 44
#define UT 44
#define USTR 52

// r24: packed-FMA attack. MI355X FP32 peak (157.3TF) REQUIRES
// v_pk_fma_f32 (VOP3P, 2 FMA/instr); scalar v_fma issues at half rate.
// With occupancy saturated (r17/r20), memory pipes non-critical
// (r14/r15/r22 A/Bs all neutral), and staging deleted (r23), issue
// count is the remaining axis. conv1 packs the 2 channels into f32x2
// lanes (window = splat, weight-pair = real 64b operand from a
// pre-packed table -> no packing moves); conv2 packs the 2 output
// rows (phi window shared, (w_row0,w_row1) pre-packed, zero-padded at
// dyt edges; +0.0 adds are bit-exact). Per-accumulator FMA order
// preserved -> bit-identical (absmax 0.015625).
// Hard-won constraints (do not violate):
//  - all per-lane accumulators NAMED SCALARS/vectors (r3)
//  - conv1 dy loop unroll-pinned, SW row-pipeline kept (r17/r20/r21)
//  - 4-px-wide items (r6); atomic combine loses 34us (r13)
//  - gather pipe speed-invariant (r14/r15); table fusion into main
//    loses (r16); occupancy saturates ~16-24 waves/CU (r17/r20)
//  - 2x4 work/thread wins (r21); LDS bank conflicts NOT critical (r22)
//  - direct-global conv1 from padded-u wins (r23)

typedef float f32x2 __attribute__((ext_vector_type(2)));

__device__ __forceinline__ f32x2 splat2(float v) {
    f32x2 r; r.x = v; r.y = v; return r;
}
__device__ __forceinline__ f32x2 pkfma(f32x2 a, f32x2 b, f32x2 c) {
    return __builtin_elementwise_fma(a, b, c);
}

// ---- prep: pad u (all 578 blocks), tables (blocks 0..47),
//      packed conv1 weights (block 48), packed conv2 weights (block 49) ----
__global__ __launch_bounds__(256)
void tnrd_prep(const float* __restrict__ wr,
               const float* __restrict__ u,
               const float* __restrict__ wf,
               float2* __restrict__ tab,
               float* __restrict__ upad,
               float2* __restrict__ pw1,
               float2* __restrict__ pw2)
{
    const int bid = blockIdx.x;
    const int tid = threadIdx.x;
    // pad work: 578*256 == 2*272*272 exactly
    {
        const int i = bid * 256 + tid;
        const int img = i / (PADW * PADW);
        const int rem = i - img * (PADW * PADW);
        const int py = rem / PADW, px = rem - py * PADW;
        const int gy = py - 6, gx = px - 6;
        float v = 0.f;
        if ((unsigned)gy < HH && (unsigned)gx < WW)
            v = u[img * (HH * WW) + gy * WW + gx];
        upad[i] = v;
    }
    if (bid < NC && tid < TP) {        // phi tables
        const int j = tid;
        const float* rc = wr + bid * NB;
        float v0 = 0.f, v1 = 0.f;
        float x0 = fmaf((float)j, 1.0f / 64.0f, -1.5f);
        float x1 = x0 + 1.0f / 64.0f;
        #pragma unroll
        for (int k = 0; k < NB; ++k) {
            float mu = -1.f + (float)k * (1.f / 15.f);
            float d0 = x0 - mu, d1 = x1 - mu;
            float w = rc[k];
            v0 = fmaf(w, __expf(-50.f * d0 * d0), v0);
            v1 = fmaf(w, __expf(-50.f * d1 * d1), v1);
        }
        tab[bid * TP + j] = make_float2(v0, v1 - v0);
    }
    if (bid == 48) {                   // conv1 packed weights [24][49]
        for (int i = tid; i < PW1N; i += 256) {
            int pr = i / 49, k = i - pr * 49;
            pw1[i] = make_float2(wf[(2 * pr) * 49 + k],
                                 wf[(2 * pr + 1) * 49 + k]);
        }
    }
    if (bid == 49) {                   // conv2 packed weights [48][8][7]
        for (int i = tid; i < PW2N; i += 256) {
            int c = i / 56, r = i - c * 56;
            int dyt = r / 7, wi = r - dyt * 7;
            float lo = (dyt < 7) ? wf[c * 49 + (6 - dyt) * 7 + wi] : 0.f;
            float hi = (dyt > 0) ? wf[c * 49 + (7 - dyt) * 7 + wi] : 0.f;
            pw2[i] = make_float2(lo, hi);
        }
    }
}

// standalone table kernel for the legacy fallback path
__global__ __launch_bounds__(256)
void tnrd_table(const float* __restrict__ wr, float2* __restrict__ tab)
{
    const int ch = blockIdx.x;
    const float* rc = wr + ch * NB;
    for (int j = threadIdx.x; j < TP; j += 256) {
        float v0 = 0.f, v1 = 0.f;
        float x0 = fmaf((float)j, 1.0f / 64.0f, -1.5f);
        float x1 = x0 + 1.0f / 64.0f;
        #pragma unroll
        for (int k = 0; k < NB; ++k) {
            float mu = -1.f + (float)k * (1.f / 15.f);
            float d0 = x0 - mu, d1 = x1 - mu;
            float w = rc[k];
            v0 = fmaf(w, __expf(-50.f * d0 * d0), v0);
            v1 = fmaf(w, __expf(-50.f * d1 * d1), v1);
        }
        tab[ch * TP + j] = make_float2(v0, v1 - v0);
    }
}

// ---- packed conv1 step: ab_i += splat(s_i) * (wa,wb)[WI] ----
#define F1STEPP(WI, s0, s1, s2, s3)                                     \
    { f32x2 w_ = wp[WI];                                                \
      ab0 = pkfma(splat2(s0), w_, ab0);                                 \
      ab1 = pkfma(splat2(s1), w_, ab1);                                 \
      ab2 = pkfma(splat2(s2), w_, ab2);                                 \
      ab3 = pkfma(splat2(s3), w_, ab3); }

// 7 taps over the 10-float window (q0.xyzw q1.xyzw q2.xy)
#define F1ROWP(WPROW, q0, q1, q2)                                       \
    { const f32x2* wp = (WPROW);                                        \
      F1STEPP(0, q0.x, q0.y, q0.z, q0.w)                                \
      F1STEPP(1, q0.y, q0.z, q0.w, q1.x)                                \
      F1STEPP(2, q0.z, q0.w, q1.x, q1.y)                                \
      F1STEPP(3, q0.w, q1.x, q1.y, q1.z)                                \
      F1STEPP(4, q1.x, q1.y, q1.z, q1.w)                                \
      F1STEPP(5, q1.y, q1.z, q1.w, q2.x)                                \
      F1STEPP(6, q1.z, q1.w, q2.x, q2.y) }

// table lerp from global (L1-resident 18KB table), named temps only
#define LERP1(res, aval, T)                                             \
    { float t_ = fminf(fmaxf(fmaf(aval, 64.f, 96.f), 0.f), 191.999f);   \
      float fj_ = floorf(t_);                                           \
      float2 e_ = (T)[(int)fj_];            /* global_load_dwordx2 */   \
      res = fmaf(t_ - fj_, e_.y, e_.x); }

// ---- packed conv2 step: oo_j += splat(aw)*wpa[WI] ; += splat(bw)*wpb[WI]
#define C2STEPP(WI, s0, s1, s2, s3, t0, t1, t2, t3)                     \
    { f32x2 wa_ = wpa[WI], wb_ = wpb[WI];                               \
      oo0 = pkfma(splat2(s0), wa_, oo0);                                \
      oo1 = pkfma(splat2(s1), wa_, oo1);                                \
      oo2 = pkfma(splat2(s2), wa_, oo2);                                \
      oo3 = pkfma(splat2(s3), wa_, oo3);                                \
      oo0 = pkfma(splat2(t0), wb_, oo0);                                \
      oo1 = pkfma(splat2(t1), wb_, oo1);                                \
      oo2 = pkfma(splat2(t2), wb_, oo2);                                \
      oo3 = pkfma(splat2(t3), wb_, oo3); }

#define C2SWEEPP()                                                      \
    C2STEPP(6, A0.x, A0.y, A0.z, A0.w, B0.x, B0.y, B0.z, B0.w)          \
    C2STEPP(5, A0.y, A0.z, A0.w, A1.x, B0.y, B0.z, B0.w, B1.x)          \
    C2STEPP(4, A0.z, A0.w, A1.x, A1.y, B0.z, B0.w, B1.x, B1.y)          \
    C2STEPP(3, A0.w, A1.x, A1.y, A1.z, B0.w, B1.x, B1.y, B1.z)          \
    C2STEPP(2, A1.x, A1.y, A1.z, A1.w, B1.x, B1.y, B1.z, B1.w)          \
    C2STEPP(1, A1.y, A1.z, A1.w, A2.x, B1.y, B1.z, B1.w, B2.x)          \
    C2STEPP(0, A1.z, A1.w, A2.x, A2.y, B1.z, B1.w, B2.x, B2.y)

// ---- main kernel: 2ch/block, 32x64 tile, 2x4 px/thread, packed FMA ----
__global__ __launch_bounds__(256, 6)
void tnrd_main_pk(const float* __restrict__ upad,  // padded u [2][272][272]
                  const f32x2* __restrict__ pw1,   // [24][49] (wA,wB)
                  const f32x2* __restrict__ pw2,   // [48][8][7] (w_r0,w_r1)
                  const float2* __restrict__ tab,  // phi tables [48][TP]
                  float* __restrict__ part)
{
    __shared__ __align__(16) float phi_s[2][PTY * PSTR2];   // 23104 B

    const int tid = threadIdx.x;
    const int bx = blockIdx.x, by = blockIdx.y;          // 4 x 8 tiles
    const int b = blockIdx.z / 24, g = blockIdx.z % 24;
    const int c0 = g * 2;

    const int py0 = by * OTY - 3, px0 = bx * OTX - 3;

    // ---- conv1 + RBF lerp into planes phi_s[0]/phi_s[1] ----
    {
        const f32x2* wpb0 = pw1 + g * 49;          // block-uniform
        const float2* tA = tab + c0 * TP;          // global, L1-hot
        const float2* tB = tA + TP;
        const float* ubase = upad + b * (PADW * PADW);
        // 684 items = 38 rows x 18 col-strips, row-major
        for (int p = 0; p < 3; ++p) {
            const int gi = tid + p * 256;
            if (gi < N1ITEM) {
                const int pr = gi / 18, pc = (gi % 18) * 4;
                f32x2 ab0 = {0.f, 0.f}, ab1 = {0.f, 0.f};
                f32x2 ab2 = {0.f, 0.f}, ab3 = {0.f, 0.f};
                // window row dy at padded row (py0+pr+3+dy), col bx*64+pc
                const float* bptr = ubase + (py0 + pr + 3) * PADW
                                          + (bx * OTX + pc);

                // software pipeline: load row dy+1 before consuming row dy
                float4 c0v = *(const float4*)(bptr);
                float4 c1v = *(const float4*)(bptr + 4);
                float2 c2v = *(const float2*)(bptr + 8);
                #pragma unroll 1
                for (int dy = 0; dy < 6; ++dy) {
                    const float* nr = bptr + (dy + 1) * PADW;
                    float4 n0 = *(const float4*)(nr);
                    float4 n1 = *(const float4*)(nr + 4);
                    float2 n2 = *(const float2*)(nr + 8);
                    F1ROWP(wpb0 + dy * 7, c0v, c1v, c2v)
                    c0v = n0; c1v = n1; c2v = n2;
                }
                F1ROWP(wpb0 + 42, c0v, c1v, c2v)   // epilogue dy=6

                // ---- 1-gather lerp; phi = 0 outside image ----
                const int gy = py0 + pr;
                const bool rowok = (unsigned)gy < HH;
                const bool ok0 = rowok && (unsigned)(px0 + pc + 0) < WW;
                const bool ok1 = rowok && (unsigned)(px0 + pc + 1) < WW;
                const bool ok2 = rowok && (unsigned)(px0 + pc + 2) < WW;
                const bool ok3 = rowok && (unsigned)(px0 + pc + 3) < WW;
                float pA0, pA1, pA2, pA3, pB0, pB1, pB2, pB3;
                LERP1(pA0, ab0.x, tA) LERP1(pB0, ab0.y, tB)
                LERP1(pA1, ab1.x, tA) LERP1(pB1, ab1.y, tB)
                LERP1(pA2, ab2.x, tA) LERP1(pB2, ab2.y, tB)
                LERP1(pA3, ab3.x, tA) LERP1(pB3, ab3.y, tB)
                pA0 = ok0 ? pA0 : 0.f;  pB0 = ok0 ? pB0 : 0.f;
                pA1 = ok1 ? pA1 : 0.f;  pB1 = ok1 ? pB1 : 0.f;
                pA2 = ok2 ? pA2 : 0.f;  pB2 = ok2 ? pB2 : 0.f;
                pA3 = ok3 ? pA3 : 0.f;  pB3 = ok3 ? pB3 : 0.f;
                *(float4*)(&phi_s[0][pr * PSTR2 + pc]) =
                    make_float4(pA0, pA1, pA2, pA3);      // ds_write_b128
                *(float4*)(&phi_s[1][pr * PSTR2 + pc]) =
                    make_float4(pB0, pB1, pB2, pB3);      // ds_write_b128
            }
        }
    }
    __syncthreads();

    // ---- conv2: 2x4 px/thread, rows packed into f32x2 lanes ----
    {
        const int tr = tid >> 4;        // 0..15 -> rows 2tr, 2tr+1
        const int ox = (tid & 15) * 4;  // 0..60
        f32x2 oo0 = {0.f, 0.f}, oo1 = {0.f, 0.f};
        f32x2 oo2 = {0.f, 0.f}, oo3 = {0.f, 0.f};

        // rows: lane.x = output row 2tr (weights (6-dyt), 0 at dyt=7),
        //       lane.y = output row 2tr+1 (weights (7-dyt), 0 at dyt=0)
        #pragma unroll
        for (int dyt = 0; dyt < 8; ++dyt) {
            const float* rA = &phi_s[0][(2 * tr + dyt) * PSTR2 + ox];
            const float* rB = &phi_s[1][(2 * tr + dyt) * PSTR2 + ox];
            const float4 A0 = *(const float4*)(rA);
            const float4 A1 = *(const float4*)(rA + 4);
            const float2 A2 = *(const float2*)(rA + 8);
            const float4 B0 = *(const float4*)(rB);
            const float4 B1 = *(const float4*)(rB + 4);
            const float2 B2 = *(const float2*)(rB + 8);
            const f32x2* wpa = pw2 + (size_t)c0 * 56 + dyt * 7;
            const f32x2* wpb = wpa + 56;
            C2SWEEPP()
        }

        const int gy0 = by * OTY + 2 * tr, gx = bx * OTX + ox;
        float* dst = part + (size_t)g * NPIX + b * (HH * WW) + gy0 * WW + gx;
        *reinterpret_cast<float4*>(dst) =
            make_float4(oo0.x, oo1.x, oo2.x, oo3.x);
        *reinterpret_cast<float4*>(dst + WW) =
            make_float4(oo0.y, oo1.y, oo2.y, oo3.y);
    }
}

// ==== legacy fallback (proven r17/r20 device code) ====
#define F1STEP(WI, s0, s1, s2, s3)                                      \
    { float fa = wa[WI], fb = wb[WI];                                   \
      a0 = fmaf(s0, fa, a0); a1 = fmaf(s1, fa, a1);                     \
      a2 = fmaf(s2, fa, a2); a3 = fmaf(s3, fa, a3);                     \
      b0 = fmaf(s0, fb, b0); b1 = fmaf(s1, fb, b1);                     \
      b2 = fmaf(s2, fb, b2); b3 = fmaf(s3, fb, b3); }

#define F1ROW(WA, WB, q0, q1, q2)                                       \
    { const float* wa = (WA); const float* wb = (WB);                   \
      F1STEP(0, q0.x, q0.y, q0.z, q0.w)                                 \
      F1STEP(1, q0.y, q0.z, q0.w, q1.x)                                 \
      F1STEP(2, q0.z, q0.w, q1.x, q1.y)                                 \
      F1STEP(3, q0.w, q1.x, q1.y, q1.z)                                 \
      F1STEP(4, q1.x, q1.y, q1.z, q1.w)                                 \
      F1STEP(5, q1.y, q1.z, q1.w, q2.x)                                 \
      F1STEP(6, q1.z, q1.w, q2.x, q2.y) }

#define C2STEP(WI, s0, s1, s2, s3, t0, t1, t2, t3)                      \
    { float fa = wra[WI], fb = wrb[WI];                                 \
      o0 = fmaf(s0, fa, o0); o1 = fmaf(s1, fa, o1);                     \
      o2 = fmaf(s2, fa, o2); o3 = fmaf(s3, fa, o3);                     \
      o0 = fmaf(t0, fb, o0); o1 = fmaf(t1, fb, o1);                     \
      o2 = fmaf(t2, fb, o2); o3 = fmaf(t3, fb, o3); }

template<int CPG>
__global__ __launch_bounds__(256, 6)
void tnrd_main(const float* __restrict__ u,
               const float* __restrict__ wf,
               const float2* __restrict__ tab,
               float* __restrict__ part)
{
    constexpr int NGRP = NC / CPG;
    constexpr int NPASS = CPG / 2;
    __shared__ __align__(16) float u_s[UT * USTR];
    __shared__ __align__(16) float phi_s[2][PT * PSTR];

    const int tid = threadIdx.x;
    const int bx = blockIdx.x, by = blockIdx.y;
    const int b = blockIdx.z / NGRP, g = blockIdx.z % NGRP;
    const int c0g = g * CPG;

    const int uy0 = by * OT - 6, ux0 = bx * OT - 6;
    const float* ub = u + b * (HH * WW);
    for (int i = tid; i < UT * USTR; i += 256) {
        int r = i / USTR, c = i - r * USTR;
        int gy = uy0 + r, gx = ux0 + c;
        float v = 0.f;
        if (c < UT && (unsigned)gy < HH && (unsigned)gx < WW)
            v = ub[gy * WW + gx];
        u_s[i] = v;
    }
    __syncthreads();

    const int oy = tid >> 3;
    const int ox0 = (tid & 7) * 4;
    float o0 = 0.f, o1 = 0.f, o2 = 0.f, o3 = 0.f;
    const int py0 = by * OT - 3, px0 = bx * OT - 3;

    auto conv1_pass = [&](int cp, float* __restrict__ bufA,
                          float* __restrict__ bufB) {
        const float* wA = wf + (c0g + 2 * cp) * 49;
        const float* wB = wA + 49;
        const float2* tA = tab + (c0g + 2 * cp) * TP;
        const float2* tB = tA + TP;
        for (int p = 0; p < 2; ++p) {
            const int gi = tid + p * 256;
            if (gi < PT * 10) {
                const int pr = gi % PT, pc = (gi / PT) * 4;
                float a0 = 0.f, a1 = 0.f, a2 = 0.f, a3 = 0.f;
                float b0 = 0.f, b1 = 0.f, b2 = 0.f, b3 = 0.f;
                const float* bptr = &u_s[pr * USTR + pc];
                float4 c0 = *(const float4*)(bptr);
                float4 c1 = *(const float4*)(bptr + 4);
                float2 c2 = *(const float2*)(bptr + 8);
                #pragma unroll 1
                for (int dy = 0; dy < 6; ++dy) {
                    const float* nr = bptr + (dy + 1) * USTR;
                    float4 n0 = *(const float4*)(nr);
                    float4 n1 = *(const float4*)(nr + 4);
                    float2 n2 = *(const float2*)(nr + 8);
                    F1ROW(wA + dy * 7, wB + dy * 7, c0, c1, c2)
                    c0 = n0; c1 = n1; c2 = n2;
                }
                F1ROW(wA + 42, wB + 42, c0, c1, c2)
                const int gy = py0 + pr;
                const bool rowok = (unsigned)gy < HH;
                const bool ok0 = rowok && (unsigned)(px0 + pc + 0) < WW;
                const bool ok1 = rowok && (unsigned)(px0 + pc + 1) < WW;
                const bool ok2 = rowok && (unsigned)(px0 + pc + 2) < WW;
                const bool ok3 = rowok && (unsigned)(px0 + pc + 3) < WW;
                float pA0, pA1, pA2, pA3, pB0, pB1, pB2, pB3;
                LERP1(pA0, a0, tA) LERP1(pB0, b0, tB)
                LERP1(pA1, a1, tA) LERP1(pB1, b1, tB)
                LERP1(pA2, a2, tA) LERP1(pB2, b2, tB)
                LERP1(pA3, a3, tA) LERP1(pB3, b3, tB)
                pA0 = ok0 ? pA0 : 0.f;  pB0 = ok0 ? pB0 : 0.f;
                pA1 = ok1 ? pA1 : 0.f;  pB1 = ok1 ? pB1 : 0.f;
                pA2 = ok2 ? pA2 : 0.f;  pB2 = ok2 ? pB2 : 0.f;
                pA3 = ok3 ? pA3 : 0.f;  pB3 = ok3 ? pB3 : 0.f;
                *(float4*)(bufA + pr * PSTR + pc) =
                    make_float4(pA0, pA1, pA2, pA3);
                *(float4*)(bufB + pr * PSTR + pc) =
                    make_float4(pB0, pB1, pB2, pB3);
            }
        }
    };

    #pragma unroll 1
    for (int pass = 0; pass < NPASS; ++pass) {
        conv1_pass(pass, phi_s[0], phi_s[1]);
        __syncthreads();
        const float* wA = wf + (c0g + 2 * pass) * 49;
        const float* wB = wA + 49;
        const float* pA = phi_s[0];
        const float* pB = phi_s[1];
        for (int dy = 0; dy < 7; ++dy) {
            const float* rA = pA + (oy + dy) * PSTR + ox0;
            const float* rB = pB + (oy + dy) * PSTR + ox0;
            const float4 A0 = *(const float4*)(rA);
            const float4 A1 = *(const float4*)(rA + 4);
            const float2 A2 = *(const float2*)(rA + 8);
            const float4 B0 = *(const float4*)(rB);
            const float4 B1 = *(const float4*)(rB + 4);
            const float2 B2 = *(const float2*)(rB + 8);
            const float* wra = wA + (6 - dy) * 7;
            const float* wrb = wB + (6 - dy) * 7;
            C2STEP(6, A0.x, A0.y, A0.z, A0.w, B0.x, B0.y, B0.z, B0.w)
            C2STEP(5, A0.y, A0.z, A0.w, A1.x, B0.y, B0.z, B0.w, B1.x)
            C2STEP(4, A0.z, A0.w, A1.x, A1.y, B0.z, B0.w, B1.x, B1.y)
            C2STEP(3, A0.w, A1.x, A1.y, A1.z, B0.w, B1.x, B1.y, B1.z)
            C2STEP(2, A1.x, A1.y, A1.z, A1.w, B1.x, B1.y, B1.z, B1.w)
            C2STEP(1, A1.y, A1.z, A1.w, A2.x, B1.y, B1.z, B1.w, B2.x)
            C2STEP(0, A1.z, A1.w, A2.x, A2.y, B1.z, B1.w, B2.x, B2.y)
        }
        if (pass < NPASS - 1) __syncthreads();
    }

    const int gy = by * OT + oy, gx = bx * OT + ox0;
    float4 v4 = make_float4(o0, o1, o2, o3);
    *reinterpret_cast<float4*>(part + (size_t)g * NPIX + b * (HH * WW)
                               + gy * WW + gx) = v4;
}

template<int NGRP>
__global__ __launch_bounds__(256)
void combine_kernel(const float* __restrict__ u,
                    const float* __restrict__ f,
                    const float* __restrict__ lam,
                    const float* __restrict__ part,
                    float* __restrict__ out)
{
    int i = blockIdx.x * 256 + threadIdx.x;  // 512 blocks -> NPIX
    float d = 0.f;
    #pragma unroll
    for (int g = 0; g < NGRP; ++g) d += part[g * NPIX + i];
    float lv = lam[0];
    float uv = u[i];
    float fv = f[i];
    out[i] = uv - d - lv * (uv - fv);
}

extern "C" void kernel_launch(void* const* d_in, const int* in_sizes, int n_in,
                              void* d_out, int out_size, void* d_ws, size_t ws_size,
                              hipStream_t stream) {
    const float* u    = (const float*)d_in[0];
    const float* f    = (const float*)d_in[1];
    const float* filt = (const float*)d_in[2];
    const float* rbfw = (const float*)d_in[3];
    const float* lam  = (const float*)d_in[4];
    float* out = (float*)d_out;
    float* part = (float*)d_ws;
    // phi tables overlaid on d_out scratch (48*192 float2 = 18432 floats
    // <= 131072); combine_kernel fully overwrites d_out afterwards.
    float2* tabg = (float2*)d_out;

    float* upad = part + (size_t)24 * NPIX;
    float* pw1f = upad + PADN;
    float* pw2f = pw1f + 2 * PW1N;
    const size_t need =
        ((size_t)24 * NPIX + PADN + 2 * PW1N + 2 * PW2N) * sizeof(float);
    if (ws_size >= need) {
        // prep: pad u (578 blocks; 48 also build tables, 48/49 pack weights)
        tnrd_prep<<<PADN / 256, 256, 0, stream>>>(
            rbfw, u, filt, tabg, upad, (float2*)pw1f, (float2*)pw2f);
        // 24 groups x 2ch, 32x64 tiles, 2x4 px/thread, packed FMA
        tnrd_main_pk<<<dim3(WW / OTX, HH / OTY, 48), 256, 0, stream>>>(
            upad, (const f32x2*)pw1f, (const f32x2*)pw2f, tabg, part);
        combine_kernel<24><<<512, 256, 0, stream>>>(u, f, lam, part, out);
    } else if (ws_size >= (size_t)12 * NPIX * sizeof(float)) {
        // r17 structure: 12 groups x 4ch, 6 blocks/CU
        tnrd_table<<<NC, 256, 0, stream>>>(rbfw, tabg);
        tnrd_main<4><<<dim3(8, 8, 24), 256, 0, stream>>>(u, filt, tabg, part);
        combine_kernel<12><<<512, 256, 0, stream>>>(u, f, lam, part, out);
    } else {
        // smallest-ws fallback: 6 groups x 8ch (r15 structure)
        tnrd_table<<<NC, 256, 0, stream>>>(rbfw, tabg);
        tnrd_main<8><<<dim3(8, 8, 12), 256, 0, stream>>>(u, filt, tabg, part);
        combine_kernel<6><<<512, 256, 0, stream>>>(u, f, lam, part, out);
    }
}

// Round 11
// 95.037 us; speedup vs baseline: 1.0727x; 1.0084x over previous
//
#include <hip/hip_runtime.h>

#define HH 256
#define WW 256
#define NPIX (2 * HH * WW)   // 131072 (B=2)
#define NC 48
#define NB 31
#define TP 192        // table pairs per channel: x in [-1.5,1.5], h=1/64

// ---- main-path geometry: 32x64 output tile, 2x4 px per thread ----
#define OTY 32
#define OTX 64
#define PTY 38        // phi tile rows = OTY+6
#define PSTR2 76      // phi stride (f32)
#define N1ITEM 684    // conv1 items: 38 rows x 18 col-strips

// ---- padded-u buffer: pad=6 on all sides ----
#define PADW 272
#define PADN (2 * PADW * PADW)   // 147968 floats

// packed weight tables (built in prep kernel)
#define PW1N (24 * 49)       // conv1: (wA[k], wB[k]) per channel-pair
#define PW2N (48 * 8 * 7)    // conv2: (w_row0, w_row1) per ch, dyt, wi

// ---- legacy (fallback) geometry ----
#define OT 32
#define PT 38
#define PSTR 44
#define UT 44
#define USTR 52

// r25: latency-pipeline attack. r24 proved stall-bound (packed FMA cut
// conv issues 40%, time only -5%; issue floor ~15K cy/CU vs ~80K
// measured; TLP grid-capped at 24 waves/CU). Two in-wave exposure
// points fixed, scheduling ONLY (arith order untouched -> bit-identical):
//  (1) gathers back to LDS (stage 2 tables, 3KB; r14/r15: LDS==global
//      throughput) so gathers use lgkmcnt while conv window loads use
//      vmcnt -> independent counters; THEN cross-item SW pipeline:
//      conv(k) -> issue gathers(k) -> conv(k+1) -> finish(k). Each
//      item's gather latency hides under next item's FMAs.
//  (2) conv2 rolling-window prefetch: dyt+1 ds_reads issued before
//      dyt's FMAs.
// LDS 26.2KB still 6 blocks/CU. VGPR ~80 at peak vs 85 cap -- spill
// would show as regression -> revert.
// Hard-won constraints (do not violate):
//  - all per-lane accumulators NAMED SCALARS/vectors (r3)
//  - conv1 dy loop unroll-pinned, SW row-pipeline kept (r17/r20/r21)
//  - 4-px-wide items (r6); atomic combine loses 34us (r13)
//  - gather pipe speed-invariant (r14/r15); occupancy grid-capped at
//    6 blocks/CU (r17/r20); 2x4 work/thread wins (r21); LDS bank
//    conflicts NOT critical (r22); direct-global conv1 wins (r23);
//    packed FMA wins small => latency-bound (r24)

typedef float f32x2 __attribute__((ext_vector_type(2)));

__device__ __forceinline__ f32x2 splat2(float v) {
    f32x2 r; r.x = v; r.y = v; return r;
}
__device__ __forceinline__ f32x2 pkfma(f32x2 a, f32x2 b, f32x2 c) {
    return __builtin_elementwise_fma(a, b, c);
}

// ---- prep: pad u (all 578 blocks), tables (blocks 0..47),
//      packed conv1 weights (block 48), packed conv2 weights (block 49) ----
__global__ __launch_bounds__(256)
void tnrd_prep(const float* __restrict__ wr,
               const float* __restrict__ u,
               const float* __restrict__ wf,
               float2* __restrict__ tab,
               float* __restrict__ upad,
               float2* __restrict__ pw1,
               float2* __restrict__ pw2)
{
    const int bid = blockIdx.x;
    const int tid = threadIdx.x;
    {
        const int i = bid * 256 + tid;
        const int img = i / (PADW * PADW);
        const int rem = i - img * (PADW * PADW);
        const int py = rem / PADW, px = rem - py * PADW;
        const int gy = py - 6, gx = px - 6;
        float v = 0.f;
        if ((unsigned)gy < HH && (unsigned)gx < WW)
            v = u[img * (HH * WW) + gy * WW + gx];
        upad[i] = v;
    }
    if (bid < NC && tid < TP) {        // phi tables
        const int j = tid;
        const float* rc = wr + bid * NB;
        float v0 = 0.f, v1 = 0.f;
        float x0 = fmaf((float)j, 1.0f / 64.0f, -1.5f);
        float x1 = x0 + 1.0f / 64.0f;
        #pragma unroll
        for (int k = 0; k < NB; ++k) {
            float mu = -1.f + (float)k * (1.f / 15.f);
            float d0 = x0 - mu, d1 = x1 - mu;
            float w = rc[k];
            v0 = fmaf(w, __expf(-50.f * d0 * d0), v0);
            v1 = fmaf(w, __expf(-50.f * d1 * d1), v1);
        }
        tab[bid * TP + j] = make_float2(v0, v1 - v0);
    }
    if (bid == 48) {                   // conv1 packed weights [24][49]
        for (int i = tid; i < PW1N; i += 256) {
            int pr = i / 49, k = i - pr * 49;
            pw1[i] = make_float2(wf[(2 * pr) * 49 + k],
                                 wf[(2 * pr + 1) * 49 + k]);
        }
    }
    if (bid == 49) {                   // conv2 packed weights [48][8][7]
        for (int i = tid; i < PW2N; i += 256) {
            int c = i / 56, r = i - c * 56;
            int dyt = r / 7, wi = r - dyt * 7;
            float lo = (dyt < 7) ? wf[c * 49 + (6 - dyt) * 7 + wi] : 0.f;
            float hi = (dyt > 0) ? wf[c * 49 + (7 - dyt) * 7 + wi] : 0.f;
            pw2[i] = make_float2(lo, hi);
        }
    }
}

// standalone table kernel for the legacy fallback path
__global__ __launch_bounds__(256)
void tnrd_table(const float* __restrict__ wr, float2* __restrict__ tab)
{
    const int ch = blockIdx.x;
    const float* rc = wr + ch * NB;
    for (int j = threadIdx.x; j < TP; j += 256) {
        float v0 = 0.f, v1 = 0.f;
        float x0 = fmaf((float)j, 1.0f / 64.0f, -1.5f);
        float x1 = x0 + 1.0f / 64.0f;
        #pragma unroll
        for (int k = 0; k < NB; ++k) {
            float mu = -1.f + (float)k * (1.f / 15.f);
            float d0 = x0 - mu, d1 = x1 - mu;
            float w = rc[k];
            v0 = fmaf(w, __expf(-50.f * d0 * d0), v0);
            v1 = fmaf(w, __expf(-50.f * d1 * d1), v1);
        }
        tab[ch * TP + j] = make_float2(v0, v1 - v0);
    }
}

// ---- packed conv1 step: ab_i += splat(s_i) * (wa,wb)[WI] ----
#define F1STEPP(WI, s0, s1, s2, s3)                                     \
    { f32x2 w_ = wp[WI];                                                \
      ab0 = pkfma(splat2(s0), w_, ab0);                                 \
      ab1 = pkfma(splat2(s1), w_, ab1);                                 \
      ab2 = pkfma(splat2(s2), w_, ab2);                                 \
      ab3 = pkfma(splat2(s3), w_, ab3); }

#define F1ROWP(WPROW, q0, q1, q2)                                       \
    { const f32x2* wp = (WPROW);                                        \
      F1STEPP(0, q0.x, q0.y, q0.z, q0.w)                                \
      F1STEPP(1, q0.y, q0.z, q0.w, q1.x)                                \
      F1STEPP(2, q0.z, q0.w, q1.x, q1.y)                                \
      F1STEPP(3, q0.w, q1.x, q1.y, q1.z)                                \
      F1STEPP(4, q1.x, q1.y, q1.z, q1.w)                                \
      F1STEPP(5, q1.y, q1.z, q1.w, q2.x)                                \
      F1STEPP(6, q1.z, q1.w, q2.x, q2.y) }

// gather ISSUE: clamp/floor VALU + ds_read_b64; frac precomputed so the
// later finish is a single fma (bit-identical to old LERP1)
#define GISS(fr, e, aval, T)                                            \
    { float t_ = fminf(fmaxf(fmaf(aval, 64.f, 96.f), 0.f), 191.999f);   \
      float fj_ = floorf(t_);                                           \
      fr = t_ - fj_;                                                    \
      e = (T)[(int)fj_]; }              /* ds_read_b64, lgkmcnt */

// ---- conv1 item phase macros (suffix S distinguishes live items) ----
#define C1_CONV(S, GI)                                                  \
    const int pr##S = (GI) / 18, pc##S = ((GI) % 18) * 4;               \
    f32x2 aba##S = {0.f, 0.f}, abb##S = {0.f, 0.f},                     \
          abc##S = {0.f, 0.f}, abd##S = {0.f, 0.f};                     \
    {                                                                   \
        f32x2 &ab0 = aba##S, &ab1 = abb##S, &ab2 = abc##S, &ab3 = abd##S;\
        const float* bptr = ubase + (py0 + pr##S + 3) * PADW            \
                                  + (bx * OTX + pc##S);                 \
        float4 c0v = *(const float4*)(bptr);                            \
        float4 c1v = *(const float4*)(bptr + 4);                        \
        float2 c2v = *(const float2*)(bptr + 8);                        \
        _Pragma("unroll 1")                                             \
        for (int dy = 0; dy < 6; ++dy) {                                \
            const float* nr = bptr + (dy + 1) * PADW;                   \
            float4 n0 = *(const float4*)(nr);                           \
            float4 n1 = *(const float4*)(nr + 4);                       \
            float2 n2 = *(const float2*)(nr + 8);                       \
            F1ROWP(wpb0 + dy * 7, c0v, c1v, c2v)                        \
            c0v = n0; c1v = n1; c2v = n2;                               \
        }                                                               \
        F1ROWP(wpb0 + 42, c0v, c1v, c2v)                                \
    }

#define C1_GATHER(S)                                                    \
    float fA0##S, fA1##S, fA2##S, fA3##S, fB0##S, fB1##S, fB2##S, fB3##S;\
    float2 eA0##S, eA1##S, eA2##S, eA3##S, eB0##S, eB1##S, eB2##S, eB3##S;\
    GISS(fA0##S, eA0##S, aba##S.x, tAl) GISS(fB0##S, eB0##S, aba##S.y, tBl)\
    GISS(fA1##S, eA1##S, abb##S.x, tAl) GISS(fB1##S, eB1##S, abb##S.y, tBl)\
    GISS(fA2##S, eA2##S, abc##S.x, tAl) GISS(fB2##S, eB2##S, abc##S.y, tBl)\
    GISS(fA3##S, eA3##S, abd##S.x, tAl) GISS(fB3##S, eB3##S, abd##S.y, tBl)

#define C1_FIN(S)                                                       \
    {                                                                   \
        const int gy = py0 + pr##S;                                     \
        const bool rowok = (unsigned)gy < HH;                           \
        const bool ok0 = rowok && (unsigned)(px0 + pc##S + 0) < WW;     \
        const bool ok1 = rowok && (unsigned)(px0 + pc##S + 1) < WW;     \
        const bool ok2 = rowok && (unsigned)(px0 + pc##S + 2) < WW;     \
        const bool ok3 = rowok && (unsigned)(px0 + pc##S + 3) < WW;     \
        float pA0 = fmaf(fA0##S, eA0##S.y, eA0##S.x);                   \
        float pB0 = fmaf(fB0##S, eB0##S.y, eB0##S.x);                   \
        float pA1 = fmaf(fA1##S, eA1##S.y, eA1##S.x);                   \
        float pB1 = fmaf(fB1##S, eB1##S.y, eB1##S.x);                   \
        float pA2 = fmaf(fA2##S, eA2##S.y, eA2##S.x);                   \
        float pB2 = fmaf(fB2##S, eB2##S.y, eB2##S.x);                   \
        float pA3 = fmaf(fA3##S, eA3##S.y, eA3##S.x);                   \
        float pB3 = fmaf(fB3##S, eB3##S.y, eB3##S.x);                   \
        pA0 = ok0 ? pA0 : 0.f;  pB0 = ok0 ? pB0 : 0.f;                  \
        pA1 = ok1 ? pA1 : 0.f;  pB1 = ok1 ? pB1 : 0.f;                  \
        pA2 = ok2 ? pA2 : 0.f;  pB2 = ok2 ? pB2 : 0.f;                  \
        pA3 = ok3 ? pA3 : 0.f;  pB3 = ok3 ? pB3 : 0.f;                  \
        *(float4*)(&phi_s[0][pr##S * PSTR2 + pc##S]) =                  \
            make_float4(pA0, pA1, pA2, pA3);                            \
        *(float4*)(&phi_s[1][pr##S * PSTR2 + pc##S]) =                  \
            make_float4(pB0, pB1, pB2, pB3);                            \
    }

// ---- packed conv2 step ----
#define C2STEPP(WI, s0, s1, s2, s3, t0, t1, t2, t3)                     \
    { f32x2 wa_ = wpa[WI], wb_ = wpb[WI];                               \
      oo0 = pkfma(splat2(s0), wa_, oo0);                                \
      oo1 = pkfma(splat2(s1), wa_, oo1);                                \
      oo2 = pkfma(splat2(s2), wa_, oo2);                                \
      oo3 = pkfma(splat2(s3), wa_, oo3);                                \
      oo0 = pkfma(splat2(t0), wb_, oo0);                                \
      oo1 = pkfma(splat2(t1), wb_, oo1);                                \
      oo2 = pkfma(splat2(t2), wb_, oo2);                                \
      oo3 = pkfma(splat2(t3), wb_, oo3); }

#define C2SWEEPP()                                                      \
    C2STEPP(6, A0.x, A0.y, A0.z, A0.w, B0.x, B0.y, B0.z, B0.w)          \
    C2STEPP(5, A0.y, A0.z, A0.w, A1.x, B0.y, B0.z, B0.w, B1.x)          \
    C2STEPP(4, A0.z, A0.w, A1.x, A1.y, B0.z, B0.w, B1.x, B1.y)          \
    C2STEPP(3, A0.w, A1.x, A1.y, A1.z, B0.w, B1.x, B1.y, B1.z)          \
    C2STEPP(2, A1.x, A1.y, A1.z, A1.w, B1.x, B1.y, B1.z, B1.w)          \
    C2STEPP(1, A1.y, A1.z, A1.w, A2.x, B1.y, B1.z, B1.w, B2.x)          \
    C2STEPP(0, A1.z, A1.w, A2.x, A2.y, B1.z, B1.w, B2.x, B2.y)

// ---- main kernel: 2ch/block, 32x64 tile, 2x4 px/thread, pipelined ----
__global__ __launch_bounds__(256, 6)
void tnrd_main_pl(const float* __restrict__ upad,  // padded u [2][272][272]
                  const f32x2* __restrict__ pw1,   // [24][49] (wA,wB)
                  const f32x2* __restrict__ pw2,   // [48][8][7] (w_r0,w_r1)
                  const float2* __restrict__ tab,  // phi tables [48][TP]
                  float* __restrict__ part)
{
    __shared__ __align__(16) float phi_s[2][PTY * PSTR2];   // 23104 B
    __shared__ __align__(16) float2 tabs[2][TP];            //  3072 B

    const int tid = threadIdx.x;
    const int bx = blockIdx.x, by = blockIdx.y;          // 4 x 8 tiles
    const int b = blockIdx.z / 24, g = blockIdx.z % 24;
    const int c0 = g * 2;

    // stage this block's 2 channel tables (3 KB, L2-hot source)
    for (int i = tid; i < 2 * TP; i += 256)
        ((float2*)tabs)[i] = tab[c0 * TP + i];
    __syncthreads();

    const int py0 = by * OTY - 3, px0 = bx * OTX - 3;
    const f32x2* wpb0 = pw1 + g * 49;          // block-uniform
    const float2* tAl = tabs[0];
    const float2* tBl = tabs[1];
    const float* ubase = upad + b * (PADW * PADW);

    // ---- conv1: cross-item pipeline (gathers on lgkm overlap next
    //      item's vmcnt-based conv window loads + FMAs) ----
    {
        C1_CONV(X, tid)            // item 0 (all threads; tid < 684)
        C1_GATHER(X)
        C1_CONV(Y, tid + 256)      // item 1 (all threads; tid+256 < 684)
        C1_GATHER(Y)
        C1_FIN(X)
        if (tid < N1ITEM - 512) {  // item 2: 172 threads
            C1_CONV(Z, tid + 512)
            C1_GATHER(Z)
            C1_FIN(Y)
            C1_FIN(Z)
        } else {
            C1_FIN(Y)
        }
    }
    __syncthreads();

    // ---- conv2: 2x4 px/thread, rows packed, rolling-window prefetch ----
    {
        const int tr = tid >> 4;        // 0..15 -> rows 2tr, 2tr+1
        const int ox = (tid & 15) * 4;  // 0..60
        f32x2 oo0 = {0.f, 0.f}, oo1 = {0.f, 0.f};
        f32x2 oo2 = {0.f, 0.f}, oo3 = {0.f, 0.f};

        const float* rA0 = &phi_s[0][(2 * tr) * PSTR2 + ox];
        const float* rB0 = &phi_s[1][(2 * tr) * PSTR2 + ox];
        float4 A0c = *(const float4*)(rA0);
        float4 A1c = *(const float4*)(rA0 + 4);
        float2 A2c = *(const float2*)(rA0 + 8);
        float4 B0c = *(const float4*)(rB0);
        float4 B1c = *(const float4*)(rB0 + 4);
        float2 B2c = *(const float2*)(rB0 + 8);

        #pragma unroll
        for (int dyt = 0; dyt < 8; ++dyt) {
            float4 A0n, A1n, B0n, B1n; float2 A2n, B2n;
            if (dyt < 7) {   // prefetch next row pair before FMAs
                const float* nA = &phi_s[0][(2 * tr + dyt + 1) * PSTR2 + ox];
                const float* nB = &phi_s[1][(2 * tr + dyt + 1) * PSTR2 + ox];
                A0n = *(const float4*)(nA);
                A1n = *(const float4*)(nA + 4);
                A2n = *(const float2*)(nA + 8);
                B0n = *(const float4*)(nB);
                B1n = *(const float4*)(nB + 4);
                B2n = *(const float2*)(nB + 8);
            }
            {
                const float4 A0 = A0c, A1 = A1c; const float2 A2 = A2c;
                const float4 B0 = B0c, B1 = B1c; const float2 B2 = B2c;
                const f32x2* wpa = pw2 + (size_t)c0 * 56 + dyt * 7;
                const f32x2* wpb = wpa + 56;
                C2SWEEPP()
            }
            if (dyt < 7) {
                A0c = A0n; A1c = A1n; A2c = A2n;
                B0c = B0n; B1c = B1n; B2c = B2n;
            }
        }

        const int gy0 = by * OTY + 2 * tr, gx = bx * OTX + ox;
        float* dst = part + (size_t)g * NPIX + b * (HH * WW) + gy0 * WW + gx;
        *reinterpret_cast<float4*>(dst) =
            make_float4(oo0.x, oo1.x, oo2.x, oo3.x);
        *reinterpret_cast<float4*>(dst + WW) =
            make_float4(oo0.y, oo1.y, oo2.y, oo3.y);
    }
}

// ==== legacy fallback (proven r17/r20 device code) ====
#define F1STEP(WI, s0, s1, s2, s3)                                      \
    { float fa = wa[WI], fb = wb[WI];                                   \
      a0 = fmaf(s0, fa, a0); a1 = fmaf(s1, fa, a1);                     \
      a2 = fmaf(s2, fa, a2); a3 = fmaf(s3, fa, a3);                     \
      b0 = fmaf(s0, fb, b0); b1 = fmaf(s1, fb, b1);                     \
      b2 = fmaf(s2, fb, b2); b3 = fmaf(s3, fb, b3); }

#define F1ROW(WA, WB, q0, q1, q2)                                       \
    { const float* wa = (WA); const float* wb = (WB);                   \
      F1STEP(0, q0.x, q0.y, q0.z, q0.w)                                 \
      F1STEP(1, q0.y, q0.z, q0.w, q1.x)                                 \
      F1STEP(2, q0.z, q0.w, q1.x, q1.y)                                 \
      F1STEP(3, q0.w, q1.x, q1.y, q1.z)                                 \
      F1STEP(4, q1.x, q1.y, q1.z, q1.w)                                 \
      F1STEP(5, q1.y, q1.z, q1.w, q2.x)                                 \
      F1STEP(6, q1.z, q1.w, q2.x, q2.y) }

#define LERP1(res, aval, T)                                             \
    { float t_ = fminf(fmaxf(fmaf(aval, 64.f, 96.f), 0.f), 191.999f);   \
      float fj_ = floorf(t_);                                           \
      float2 e_ = (T)[(int)fj_];                                        \
      res = fmaf(t_ - fj_, e_.y, e_.x); }

#define C2STEP(WI, s0, s1, s2, s3, t0, t1, t2, t3)                      \
    { float fa = wra[WI], fb = wrb[WI];                                 \
      o0 = fmaf(s0, fa, o0); o1 = fmaf(s1, fa, o1);                     \
      o2 = fmaf(s2, fa, o2); o3 = fmaf(s3, fa, o3);                     \
      o0 = fmaf(t0, fb, o0); o1 = fmaf(t1, fb, o1);                     \
      o2 = fmaf(t2, fb, o2); o3 = fmaf(t3, fb, o3); }

template<int CPG>
__global__ __launch_bounds__(256, 6)
void tnrd_main(const float* __restrict__ u,
               const float* __restrict__ wf,
               const float2* __restrict__ tab,
               float* __restrict__ part)
{
    constexpr int NGRP = NC / CPG;
    constexpr int NPASS = CPG / 2;
    __shared__ __align__(16) float u_s[UT * USTR];
    __shared__ __align__(16) float phi_s[2][PT * PSTR];

    const int tid = threadIdx.x;
    const int bx = blockIdx.x, by = blockIdx.y;
    const int b = blockIdx.z / NGRP, g = blockIdx.z % NGRP;
    const int c0g = g * CPG;

    const int uy0 = by * OT - 6, ux0 = bx * OT - 6;
    const float* ub = u + b * (HH * WW);
    for (int i = tid; i < UT * USTR; i += 256) {
        int r = i / USTR, c = i - r * USTR;
        int gy = uy0 + r, gx = ux0 + c;
        float v = 0.f;
        if (c < UT && (unsigned)gy < HH && (unsigned)gx < WW)
            v = ub[gy * WW + gx];
        u_s[i] = v;
    }
    __syncthreads();

    const int oy = tid >> 3;
    const int ox0 = (tid & 7) * 4;
    float o0 = 0.f, o1 = 0.f, o2 = 0.f, o3 = 0.f;
    const int py0 = by * OT - 3, px0 = bx * OT - 3;

    auto conv1_pass = [&](int cp, float* __restrict__ bufA,
                          float* __restrict__ bufB) {
        const float* wA = wf + (c0g + 2 * cp) * 49;
        const float* wB = wA + 49;
        const float2* tA = tab + (c0g + 2 * cp) * TP;
        const float2* tB = tA + TP;
        for (int p = 0; p < 2; ++p) {
            const int gi = tid + p * 256;
            if (gi < PT * 10) {
                const int pr = gi % PT, pc = (gi / PT) * 4;
                float a0 = 0.f, a1 = 0.f, a2 = 0.f, a3 = 0.f;
                float b0 = 0.f, b1 = 0.f, b2 = 0.f, b3 = 0.f;
                const float* bptr = &u_s[pr * USTR + pc];
                float4 c0 = *(const float4*)(bptr);
                float4 c1 = *(const float4*)(bptr + 4);
                float2 c2 = *(const float2*)(bptr + 8);
                #pragma unroll 1
                for (int dy = 0; dy < 6; ++dy) {
                    const float* nr = bptr + (dy + 1) * USTR;
                    float4 n0 = *(const float4*)(nr);
                    float4 n1 = *(const float4*)(nr + 4);
                    float2 n2 = *(const float2*)(nr + 8);
                    F1ROW(wA + dy * 7, wB + dy * 7, c0, c1, c2)
                    c0 = n0; c1 = n1; c2 = n2;
                }
                F1ROW(wA + 42, wB + 42, c0, c1, c2)
                const int gy = py0 + pr;
                const bool rowok = (unsigned)gy < HH;
                const bool ok0 = rowok && (unsigned)(px0 + pc + 0) < WW;
                const bool ok1 = rowok && (unsigned)(px0 + pc + 1) < WW;
                const bool ok2 = rowok && (unsigned)(px0 + pc + 2) < WW;
                const bool ok3 = rowok && (unsigned)(px0 + pc + 3) < WW;
                float pA0, pA1, pA2, pA3, pB0, pB1, pB2, pB3;
                LERP1(pA0, a0, tA) LERP1(pB0, b0, tB)
                LERP1(pA1, a1, tA) LERP1(pB1, b1, tB)
                LERP1(pA2, a2, tA) LERP1(pB2, b2, tB)
                LERP1(pA3, a3, tA) LERP1(pB3, b3, tB)
                pA0 = ok0 ? pA0 : 0.f;  pB0 = ok0 ? pB0 : 0.f;
                pA1 = ok1 ? pA1 : 0.f;  pB1 = ok1 ? pB1 : 0.f;
                pA2 = ok2 ? pA2 : 0.f;  pB2 = ok2 ? pB2 : 0.f;
                pA3 = ok3 ? pA3 : 0.f;  pB3 = ok3 ? pB3 : 0.f;
                *(float4*)(bufA + pr * PSTR + pc) =
                    make_float4(pA0, pA1, pA2, pA3);
                *(float4*)(bufB + pr * PSTR + pc) =
                    make_float4(pB0, pB1, pB2, pB3);
            }
        }
    };

    #pragma unroll 1
    for (int pass = 0; pass < NPASS; ++pass) {
        conv1_pass(pass, phi_s[0], phi_s[1]);
        __syncthreads();
        const float* wA = wf + (c0g + 2 * pass) * 49;
        const float* wB = wA + 49;
        const float* pA = phi_s[0];
        const float* pB = phi_s[1];
        for (int dy = 0; dy < 7; ++dy) {
            const float* rA = pA + (oy + dy) * PSTR + ox0;
            const float* rB = pB + (oy + dy) * PSTR + ox0;
            const float4 A0 = *(const float4*)(rA);
            const float4 A1 = *(const float4*)(rA + 4);
            const float2 A2 = *(const float2*)(rA + 8);
            const float4 B0 = *(const float4*)(rB);
            const float4 B1 = *(const float4*)(rB + 4);
            const float2 B2 = *(const float2*)(rB + 8);
            const float* wra = wA + (6 - dy) * 7;
            const float* wrb = wB + (6 - dy) * 7;
            C2STEP(6, A0.x, A0.y, A0.z, A0.w, B0.x, B0.y, B0.z, B0.w)
            C2STEP(5, A0.y, A0.z, A0.w, A1.x, B0.y, B0.z, B0.w, B1.x)
            C2STEP(4, A0.z, A0.w, A1.x, A1.y, B0.z, B0.w, B1.x, B1.y)
            C2STEP(3, A0.w, A1.x, A1.y, A1.z, B0.w, B1.x, B1.y, B1.z)
            C2STEP(2, A1.x, A1.y, A1.z, A1.w, B1.x, B1.y, B1.z, B1.w)
            C2STEP(1, A1.y, A1.z, A1.w, A2.x, B1.y, B1.z, B1.w, B2.x)
            C2STEP(0, A1.z, A1.w, A2.x, A2.y, B1.z, B1.w, B2.x, B2.y)
        }
        if (pass < NPASS - 1) __syncthreads();
    }

    const int gy = by * OT + oy, gx = bx * OT + ox0;
    float4 v4 = make_float4(o0, o1, o2, o3);
    *reinterpret_cast<float4*>(part + (size_t)g * NPIX + b * (HH * WW)
                               + gy * WW + gx) = v4;
}

template<int NGRP>
__global__ __launch_bounds__(256)
void combine_kernel(const float* __restrict__ u,
                    const float* __restrict__ f,
                    const float* __restrict__ lam,
                    const float* __restrict__ part,
                    float* __restrict__ out)
{
    int i = blockIdx.x * 256 + threadIdx.x;  // 512 blocks -> NPIX
    float d = 0.f;
    #pragma unroll
    for (int g = 0; g < NGRP; ++g) d += part[g * NPIX + i];
    float lv = lam[0];
    float uv = u[i];
    float fv = f[i];
    out[i] = uv - d - lv * (uv - fv);
}

extern "C" void kernel_launch(void* const* d_in, const int* in_sizes, int n_in,
                              void* d_out, int out_size, void* d_ws, size_t ws_size,
                              hipStream_t stream) {
    const float* u    = (const float*)d_in[0];
    const float* f    = (const float*)d_in[1];
    const float* filt = (const float*)d_in[2];
    const float* rbfw = (const float*)d_in[3];
    const float* lam  = (const float*)d_in[4];
    float* out = (float*)d_out;
    float* part = (float*)d_ws;
    // phi tables overlaid on d_out scratch (48*192 float2 = 18432 floats
    // <= 131072); combine_kernel fully overwrites d_out afterwards.
    float2* tabg = (float2*)d_out;

    float* upad = part + (size_t)24 * NPIX;
    float* pw1f = upad + PADN;
    float* pw2f = pw1f + 2 * PW1N;
    const size_t need =
        ((size_t)24 * NPIX + PADN + 2 * PW1N + 2 * PW2N) * sizeof(float);
    if (ws_size >= need) {
        tnrd_prep<<<PADN / 256, 256, 0, stream>>>(
            rbfw, u, filt, tabg, upad, (float2*)pw1f, (float2*)pw2f);
        tnrd_main_pl<<<dim3(WW / OTX, HH / OTY, 48), 256, 0, stream>>>(
            upad, (const f32x2*)pw1f, (const f32x2*)pw2f, tabg, part);
        combine_kernel<24><<<512, 256, 0, stream>>>(u, f, lam, part, out);
    } else if (ws_size >= (size_t)12 * NPIX * sizeof(float)) {
        tnrd_table<<<NC, 256, 0, stream>>>(rbfw, tabg);
        tnrd_main<4><<<dim3(8, 8, 24), 256, 0, stream>>>(u, filt, tabg, part);
        combine_kernel<12><<<512, 256, 0, stream>>>(u, f, lam, part, out);
    } else {
        tnrd_table<<<NC, 256, 0, stream>>>(rbfw, tabg);
        tnrd_main<8><<<dim3(8, 8, 12), 256, 0, stream>>>(u, filt, tabg, part);
        combine_kernel<6><<<512, 256, 0, stream>>>(u, f, lam, part, out);
    }
}